// Round 8
// baseline (431.717 us; speedup 1.0000x reference)
//
#include <hip/hip_runtime.h>
#include <math.h>

#define N_NODES 16384
#define B_GRAPHS 8
#define NPG_     2048
#define E_EDGES  262144
#define F_IN  128
#define F_HID 256
#define F_OUT 128
#define ICP_IT 10
#define NN_BPG 32   // blocks per graph (64 src pts/block, 512 threads)

typedef __attribute__((ext_vector_type(8))) short bf16x8;
typedef __attribute__((ext_vector_type(4))) float f32x4;

__device__ __forceinline__ float b2f(unsigned short u) {
    union { unsigned int u; float f; } v; v.u = ((unsigned int)u) << 16; return v.f;
}
__device__ __forceinline__ unsigned short f2b(float f) {
    union { float f; unsigned int u; } v; v.f = f;
    unsigned int r = v.u + 0x7FFFu + ((v.u >> 16) & 1u);
    return (unsigned short)(r >> 16);
}
// XOR swizzle within 32-element groups: spreads lane-sliced LDS scans over banks.
__device__ __forceinline__ int swz32(int i) {
    return (i & ~31) | ((i & 31) ^ ((i >> 5) & 31));
}
// Agent-scope accesses (device-coherent; validated R4-R6 pattern).
__device__ __forceinline__ void st_agent(float* p, float v) {
    __hip_atomic_store(p, v, __ATOMIC_RELAXED, __HIP_MEMORY_SCOPE_AGENT);
}
__device__ __forceinline__ float ld_agent(const float* p) {
    return __hip_atomic_load(p, __ATOMIC_RELAXED, __HIP_MEMORY_SCOPE_AGENT);
}
__device__ __forceinline__ void st_rel_i(int* p, int v) {
    __hip_atomic_store(p, v, __ATOMIC_RELEASE, __HIP_MEMORY_SCOPE_AGENT);
}
__device__ __forceinline__ int ld_acq_i(const int* p) {
    return __hip_atomic_load(p, __ATOMIC_ACQUIRE, __HIP_MEMORY_SCOPE_AGENT);
}
__device__ __forceinline__ int ld_agent_i(const int* p) {
    return __hip_atomic_load(p, __ATOMIC_RELAXED, __HIP_MEMORY_SCOPE_AGENT);
}

// ------- k_prep: x->bf16, weight transpose-converts, edge count (counts pre-zeroed
// by stream-ordered memset), zero sync ctrs ------------------------------------------------
__global__ __launch_bounds__(256) void k_prep(
    const float* __restrict__ x, unsigned short* __restrict__ xb,
    const float* __restrict__ W1, const float* __restrict__ W2, const float* __restrict__ W3,
    unsigned short* __restrict__ W1b, unsigned short* __restrict__ W2b, unsigned short* __restrict__ W3b,
    const int* __restrict__ col, int* __restrict__ counts, int* __restrict__ ctrs)
{
    const int b = blockIdx.x, tid = threadIdx.x;
    if (b < 2048) {                       // x: 524288 float4 -> uint2
        int i = b * 256 + tid;
        float4 v = ((const float4*)x)[i];
        uint2 o;
        o.x = (unsigned int)f2b(v.x) | ((unsigned int)f2b(v.y) << 16);
        o.y = (unsigned int)f2b(v.z) | ((unsigned int)f2b(v.w) << 16);
        ((uint2*)xb)[i] = o;
    } else if (b < 2176) {                // W1 [128][256] -> W1b [256][128]
        int idx = (b - 2048) * 256 + tid;
        int k = idx >> 8, n = idx & 255;
        W1b[n * 128 + k] = f2b(W1[idx]);
    } else if (b < 2432) {                // W2 [256][256] -> W2b [256][256]
        int idx = (b - 2176) * 256 + tid;
        int k = idx >> 8, n = idx & 255;
        W2b[n * 256 + k] = f2b(W2[idx]);
    } else if (b < 2560) {                // W3 [256][128] -> W3b [128][256]
        int idx = (b - 2432) * 256 + tid;
        int k = idx >> 7, n = idx & 127;
        W3b[n * 256 + k] = f2b(W3[idx]);
    } else if (b < 3584) {                // edge in-degree count
        int e = (b - 2560) * 256 + tid;
        atomicAdd(&counts[col[e]], 1);
    } else {                              // zero sync counters (512 ints)
        ctrs[tid] = 0;
        ctrs[tid + 256] = 0;
    }
}

// ---------------- CSR build ----------------
__global__ __launch_bounds__(1024) void k_scan(const int* __restrict__ counts,
        int* __restrict__ offs, int* __restrict__ cursor, float* __restrict__ dinv)
{
    __shared__ int wtot[16];
    const int t = threadIdx.x;
    const int base = t * 16;
    int local[16];
    int s = 0;
#pragma unroll
    for (int i = 0; i < 16; i++) { local[i] = counts[base + i]; s += local[i]; }
    const int lane = t & 63, w = t >> 6;
    int inc = s;                        // inclusive wave scan
    for (int o = 1; o < 64; o <<= 1) {
        int v = __shfl_up(inc, o);
        if (lane >= o) inc += v;
    }
    if (lane == 63) wtot[w] = inc;
    __syncthreads();
    if (t < 16) {
        int v = wtot[t];
        for (int o = 1; o < 16; o <<= 1) {
            int u = __shfl_up(v, o);
            if (t >= o) v += u;
        }
        wtot[t] = v;
    }
    __syncthreads();
    int run = (w > 0 ? wtot[w - 1] : 0) + (inc - s);
#pragma unroll
    for (int i = 0; i < 16; i++) {
        offs[base + i]   = run;
        cursor[base + i] = run;
        dinv[base + i]   = rsqrtf((float)(local[i] + 1));  // deg = indeg + self loop
        run += local[i];
    }
    if (t == 1023) offs[N_NODES] = run;
}

__global__ void k_scatter(const int* __restrict__ row, const int* __restrict__ col,
        int* __restrict__ cursor, const float* __restrict__ dinv,
        int* __restrict__ srcid, float* __restrict__ normv)
{
    int e = blockIdx.x * 256 + threadIdx.x;
    if (e >= E_EDGES) return;
    int r = row[e], c = col[e];
    int p = atomicAdd(&cursor[c], 1);
    srcid[p] = r;
    normv[p] = dinv[r] * dinv[c];
}

// ---------------- GCN aggregation (bf16 in, fp32 acc); unroll-4 gather; fused tpos --------
template<int W, int OUTF, int FUSET>
__global__ __launch_bounds__(128) void k_agg(const unsigned short* __restrict__ X,
        void* __restrict__ Y,
        const int* __restrict__ offs, const int* __restrict__ srcid,
        const float* __restrict__ normv, const float* __restrict__ dinv,
        const float* __restrict__ bias, int relu,
        const float* __restrict__ Wt, const float* __restrict__ bt,
        const float* __restrict__ pos, float* __restrict__ tposO)
{
    constexpr int NPB = (W == 128) ? 2 : 1;     // nodes per block (128 threads)
    constexpr int W2 = W / 2;
    const int local = (NPB == 2) ? (threadIdx.x >> 6) : 0;
    const int n = blockIdx.x * NPB + local;
    const int j = (NPB == 2) ? (threadIdx.x & 63) : threadIdx.x;
    const unsigned int* Xu = (const unsigned int*)X;
    float di = dinv[n];
    float w0 = di * di;
    unsigned int v = Xu[(size_t)n * W2 + j];
    float a0 = b2f((unsigned short)v) * w0;
    float a1 = b2f((unsigned short)(v >> 16)) * w0;
    int p = offs[n];
    const int p1 = offs[n + 1];
    for (; p + 3 < p1; p += 4) {
        int s0i = srcid[p], s1i = srcid[p + 1], s2i = srcid[p + 2], s3i = srcid[p + 3];
        float n0 = normv[p], n1 = normv[p + 1], n2 = normv[p + 2], n3 = normv[p + 3];
        unsigned int v0 = Xu[(size_t)s0i * W2 + j];
        unsigned int v1 = Xu[(size_t)s1i * W2 + j];
        unsigned int v2 = Xu[(size_t)s2i * W2 + j];
        unsigned int v3 = Xu[(size_t)s3i * W2 + j];
        a0 = fmaf(b2f((unsigned short)v0), n0, a0);
        a1 = fmaf(b2f((unsigned short)(v0 >> 16)), n0, a1);
        a0 = fmaf(b2f((unsigned short)v1), n1, a0);
        a1 = fmaf(b2f((unsigned short)(v1 >> 16)), n1, a1);
        a0 = fmaf(b2f((unsigned short)v2), n2, a0);
        a1 = fmaf(b2f((unsigned short)(v2 >> 16)), n2, a1);
        a0 = fmaf(b2f((unsigned short)v3), n3, a0);
        a1 = fmaf(b2f((unsigned short)(v3 >> 16)), n3, a1);
    }
    for (; p < p1; ++p) {
        unsigned int va = Xu[(size_t)srcid[p] * W2 + j]; float na = normv[p];
        a0 = fmaf(b2f((unsigned short)va), na, a0);
        a1 = fmaf(b2f((unsigned short)(va >> 16)), na, a1);
    }
    if (bias) { a0 += bias[2 * j]; a1 += bias[2 * j + 1]; }
    if (relu) { a0 = fmaxf(a0, 0.f); a1 = fmaxf(a1, 0.f); }
    if (OUTF) {
        float* Yf = (float*)Y;
        Yf[(size_t)n * W + 2 * j]     = a0;
        Yf[(size_t)n * W + 2 * j + 1] = a1;
    } else {
        ((unsigned int*)Y)[(size_t)n * W2 + j] =
            (unsigned int)f2b(a0) | ((unsigned int)f2b(a1) << 16);
    }
    if (FUSET) {   // tpos = pos + h @ Wt + bt, wave-per-node (W==128 only)
        float wt0 = Wt[6 * j + 0], wt1 = Wt[6 * j + 1], wt2 = Wt[6 * j + 2];
        float wt3 = Wt[6 * j + 3], wt4 = Wt[6 * j + 4], wt5 = Wt[6 * j + 5];
        float s0 = a0 * wt0 + a1 * wt3;
        float s1 = a0 * wt1 + a1 * wt4;
        float s2 = a0 * wt2 + a1 * wt5;
        for (int o = 32; o > 0; o >>= 1) {
            s0 += __shfl_down(s0, o);
            s1 += __shfl_down(s1, o);
            s2 += __shfl_down(s2, o);
        }
        if (j == 0) {
            tposO[n * 3 + 0] = pos[n * 3 + 0] + s0 + bt[0];
            tposO[n * 3 + 1] = pos[n * 3 + 1] + s1 + bt[1];
            tposO[n * 3 + 2] = pos[n * 3 + 2] + s2 + bt[2];
        }
    }
}

// ---------------- bf16 MFMA GEMM: C[M,N] = A[M,K] @ Bt[N,K]^T (+bias,relu) ----------------
__global__ __launch_bounds__(256) void k_gemm_bf16(
    const unsigned short* __restrict__ A,   // [M][K] bf16
    const unsigned short* __restrict__ Bt,  // [N][K] bf16
    const float* __restrict__ bias, unsigned short* __restrict__ C,
    int M, int N, int K, int relu)
{
    __shared__ __align__(16) unsigned short As[128 * 64];
    __shared__ __align__(16) unsigned short Bs[64 * 64];
    const int tid  = threadIdx.x;
    const int lane = tid & 63;
    const int wave = tid >> 6;
    const int bm = blockIdx.y * 128, bn = blockIdx.x * 64;
    const int wm = (wave >> 1) * 64, wn = (wave & 1) * 32;
    f32x4 acc[4][2];
#pragma unroll
    for (int mf = 0; mf < 4; mf++)
#pragma unroll
        for (int nf = 0; nf < 2; nf++) acc[mf][nf] = (f32x4){0.f, 0.f, 0.f, 0.f};

    for (int k0 = 0; k0 < K; k0 += 64) {
#pragma unroll
        for (int i = 0; i < 4; i++) {
            int idx = i * 256 + tid;
            int m = idx >> 3, slot = idx & 7;
            const unsigned short* src = A + (size_t)(bm + m) * K + k0 + ((slot ^ (m & 7)) << 3);
            __builtin_amdgcn_global_load_lds(
                (const __attribute__((address_space(1))) unsigned int*)src,
                (__attribute__((address_space(3))) unsigned int*)(As + (size_t)i * 2048 + wave * 512),
                16, 0, 0);
        }
#pragma unroll
        for (int i = 0; i < 2; i++) {
            int idx = i * 256 + tid;
            int n = idx >> 3, slot = idx & 7;
            const unsigned short* src = Bt + (size_t)(bn + n) * K + k0 + ((slot ^ (n & 7)) << 3);
            __builtin_amdgcn_global_load_lds(
                (const __attribute__((address_space(1))) unsigned int*)src,
                (__attribute__((address_space(3))) unsigned int*)(Bs + (size_t)i * 2048 + wave * 512),
                16, 0, 0);
        }
        __syncthreads();
        bf16x8 af[4][2], bfr[2][2];
        const int qd = lane >> 4;
#pragma unroll
        for (int s = 0; s < 2; s++) {
#pragma unroll
            for (int mf = 0; mf < 4; mf++) {
                int m = wm + mf * 16 + (lane & 15);
                int slot = (s * 4 + qd) ^ (m & 7);
                af[mf][s] = *(const bf16x8*)(As + m * 64 + slot * 8);
            }
#pragma unroll
            for (int nf = 0; nf < 2; nf++) {
                int n = wn + nf * 16 + (lane & 15);
                int slot = (s * 4 + qd) ^ (n & 7);
                bfr[nf][s] = *(const bf16x8*)(Bs + n * 64 + slot * 8);
            }
        }
#pragma unroll
        for (int s = 0; s < 2; s++)
#pragma unroll
            for (int mf = 0; mf < 4; mf++)
#pragma unroll
                for (int nf = 0; nf < 2; nf++)
                    acc[mf][nf] = __builtin_amdgcn_mfma_f32_16x16x32_bf16(
                        af[mf][s], bfr[nf][s], acc[mf][nf], 0, 0, 0);
        __syncthreads();
    }
#pragma unroll
    for (int nf = 0; nf < 2; nf++) {
        int col = bn + wn + nf * 16 + (lane & 15);
        float bv = bias ? bias[col] : 0.f;
#pragma unroll
        for (int mf = 0; mf < 4; mf++) {
#pragma unroll
            for (int r = 0; r < 4; r++) {
                int row = bm + wm + mf * 16 + (lane >> 4) * 4 + r;
                float v = acc[mf][nf][r] + bv;
                if (relu) v = fmaxf(v, 0.f);
                C[(size_t)row * N + col] = f2b(v);
            }
        }
    }
}

// ---------------- persistent ICP (10 iters) + chamfer + loss, ONE launch ------------------
// R6 geometry (256 blocks x 512 thr, 1/CU, proven safe). NEW leader/follower sync:
// per-block release flags (no atomic convoy), graph-leader gathers+SVDs+publishes T,
// followers spin only on the T tag. T single-sourced -> bit-identical across blocks.
__global__ __launch_bounds__(512) void k_icp_all(
    const float* __restrict__ tpos, const float* __restrict__ pos,
    float* __restrict__ partials,   // [256][16]
    float* __restrict__ Tpub,       // [8][16]
    float* __restrict__ chpart,     // [256][2]
    int* __restrict__ ctrs,         // [0..255]=per-block flags, [256+g]=Ttag, [264]=chamfer
    float* __restrict__ out_aligned, float* __restrict__ out_loss)
{
    const int g = blockIdx.x >> 5, blk = blockIdx.x & 31;
    const int tid = threadIdx.x;
    const int wave = tid >> 6, lane = tid & 63;
    __shared__ float4 tq[NPG_];                                // 32KB, swizzled, w=|t|^2
    __shared__ __align__(16) unsigned char scratch[NPG_ * 16]; // 32KB union (sm_d/sm_i | al)
    float* sm_d = (float*)scratch;                             // [64][65]
    unsigned short* sm_i = (unsigned short*)(scratch + 64 * 65 * 4);
    float4* al = (float4*)scratch;                             // chamfer phase only
    __shared__ float mom[15][33];
    __shared__ float ssx[64], ssy[64], ssz[64];
    __shared__ float wred[8][2];
    __shared__ float Tsh[12];
    __shared__ double sdl[15];
    __shared__ int lastFlag;

    for (int i = tid; i < NPG_; i += 512) {
        const float* p = &pos[(size_t)(g * NPG_ + i) * 3];
        float qx = p[0], qy = p[1], qz = p[2];
        tq[swz32(i)] = make_float4(qx, qy, qz, fmaf(qx, qx, fmaf(qy, qy, qz * qz)));
    }
    if (tid < 12) Tsh[tid] = (tid == 0 || tid == 4 || tid == 8) ? 1.f : 0.f;
    // own 64 source points (8 per wave) in registers for all 10 iterations
    float Px[8], Py[8], Pz[8];
#pragma unroll
    for (int u = 0; u < 8; u++) {
        int n = g * NPG_ + blk * 64 + wave * 8 + u;
        Px[u] = tpos[n * 3 + 0]; Py[u] = tpos[n * 3 + 1]; Pz[u] = tpos[n * 3 + 2];
    }
    double Td[12];
    if (tid == 0) {
#pragma unroll
        for (int k = 0; k < 12; k++) Td[k] = (k == 0 || k == 4 || k == 8) ? 1.0 : 0.0;
    }
    __syncthreads();

    for (int iter = 0; iter < ICP_IT; ++iter) {
        float Tf[12];
#pragma unroll
        for (int k = 0; k < 12; k++) Tf[k] = Tsh[k];
        float Sx[8], Sy[8], Sz[8], Tx[8], Ty[8], Tz[8], bd[8];
        int bi[8];
#pragma unroll
        for (int u = 0; u < 8; u++) {
            float X = Tf[0] * Px[u] + Tf[1] * Py[u] + Tf[2] * Pz[u] + Tf[9];
            float Y = Tf[3] * Px[u] + Tf[4] * Py[u] + Tf[5] * Pz[u] + Tf[10];
            float Z = Tf[6] * Px[u] + Tf[7] * Py[u] + Tf[8] * Pz[u] + Tf[11];
            Sx[u] = X; Sy[u] = Y; Sz[u] = Z;
            Tx[u] = -2.f * X; Ty[u] = -2.f * Y; Tz[u] = -2.f * Z;
            bd[u] = 1e30f; bi[u] = lane * 32;
        }
        const int qbase = lane * 32;
        for (int j = 0; j < 32; j++) {
            float4 t4 = tq[qbase + (j ^ (lane & 31))];
            int idx = qbase + j;
#pragma unroll
            for (int u = 0; u < 8; u++) {
                // d' = |t|^2 - 2 s.t  (monotone in true distance)
                float d = fmaf(Tx[u], t4.x, fmaf(Ty[u], t4.y, fmaf(Tz[u], t4.z, t4.w)));
                if (d < bd[u]) { bd[u] = d; bi[u] = idx; }
            }
        }
        // stage candidates + transformed src coords
#pragma unroll
        for (int u = 0; u < 8; u++) {
            int row = wave * 8 + u;
            sm_d[row * 65 + lane] = bd[u];
            sm_i[row * 65 + lane] = (unsigned short)bi[u];
            if (lane == u) { ssx[row] = Sx[u]; ssy[row] = Sy[u]; ssz[row] = Sz[u]; }
        }
        __syncthreads();
        // wave 0: per-src argmin over 64 lane-slices (ranges ascend -> strict < = first idx),
        // then 15 block-moment shuffle sums.
        if (tid < 64) {
            const int s = tid;
            float best = sm_d[s * 65];
            int ib = sm_i[s * 65];
            for (int r = 1; r < 64; r++) {
                float dd = sm_d[s * 65 + r];
                int ii = sm_i[s * 65 + r];
                if (dd < best) { best = dd; ib = ii; }
            }
            float4 c = tq[swz32(ib)];
            float X = ssx[s], Y = ssy[s], Z = ssz[s];
            float vals[15] = { X, Y, Z, c.x, c.y, c.z,
                               X * c.x, X * c.y, X * c.z,
                               Y * c.x, Y * c.y, Y * c.z,
                               Z * c.x, Z * c.y, Z * c.z };
#pragma unroll
            for (int k = 0; k < 15; k++) {
                float v = vals[k];
                for (int o = 32; o > 0; o >>= 1) v += __shfl_down(v, o);
                if (tid == 0) st_agent(&partials[(size_t)blockIdx.x * 16 + k], v);
            }
        }
        __syncthreads();          // drains vmcnt -> partial stores done before flag
        if (tid == 0) st_rel_i(&ctrs[blockIdx.x], iter + 1);   // release: orders partials
        if (blk == 0) {
            // ---- leader: wait for all 32 block flags (parallel lanes), gather, SVD ----
            if (tid < 32) {
                while (ld_acq_i(&ctrs[g * 32 + tid]) <= iter) __builtin_amdgcn_s_sleep(1);
            }
            __syncthreads();
            if (tid < 480) {
                int kk = tid >> 5, bb = tid & 31;
                mom[kk][bb] = ld_agent(&partials[((size_t)g * 32 + bb) * 16 + kk]);
            }
            __syncthreads();
            if (tid < 15) {
                double acc = 0;
                for (int b = 0; b < NN_BPG; b++) acc += (double)mom[tid][b];
                sdl[tid] = acc;
            }
            __syncthreads();
            if (tid == 0) {
                double sd[15];
#pragma unroll
                for (int k = 0; k < 15; k++) sd[k] = sdl[k];
                const double n = (double)NPG_;
                const double rin = 1.0 / (double)NPG_;
                double cs0 = sd[0] * rin, cs1 = sd[1] * rin, cs2 = sd[2] * rin;
                double cc0 = sd[3] * rin, cc1 = sd[4] * rin, cc2 = sd[5] * rin;
                float H[3][3];
                H[0][0] = (float)(sd[6]  - n * cs0 * cc0); H[0][1] = (float)(sd[7]  - n * cs0 * cc1); H[0][2] = (float)(sd[8]  - n * cs0 * cc2);
                H[1][0] = (float)(sd[9]  - n * cs1 * cc0); H[1][1] = (float)(sd[10] - n * cs1 * cc1); H[1][2] = (float)(sd[11] - n * cs1 * cc2);
                H[2][0] = (float)(sd[12] - n * cs2 * cc0); H[2][1] = (float)(sd[13] - n * cs2 * cc1); H[2][2] = (float)(sd[14] - n * cs2 * cc2);
                double R[3][3];
                float fn = 1e-30f;
                for (int i = 0; i < 3; i++) for (int j2 = 0; j2 < 3; j2++) fn += H[i][j2] * H[i][j2];
                float sc = rsqrtf(fn);
                float Xm[3][3];
                for (int i = 0; i < 3; i++) for (int j2 = 0; j2 < 3; j2++) Xm[i][j2] = H[i][j2] * sc;
                float dX = Xm[0][0] * (Xm[1][1]*Xm[2][2] - Xm[1][2]*Xm[2][1])
                         - Xm[0][1] * (Xm[1][0]*Xm[2][2] - Xm[1][2]*Xm[2][0])
                         + Xm[0][2] * (Xm[1][0]*Xm[2][1] - Xm[1][1]*Xm[2][0]);
                if (dX > 1e-4f) {
                    // polar Newton: X <- 0.5*(X + cof(X)/det(X)); R_ref = Q^T
                    for (int itn = 0; itn < 16; ++itn) {
                        float C00 = Xm[1][1]*Xm[2][2] - Xm[1][2]*Xm[2][1];
                        float C01 = Xm[1][2]*Xm[2][0] - Xm[1][0]*Xm[2][2];
                        float C02 = Xm[1][0]*Xm[2][1] - Xm[1][1]*Xm[2][0];
                        float C10 = Xm[2][1]*Xm[0][2] - Xm[2][2]*Xm[0][1];
                        float C11 = Xm[2][2]*Xm[0][0] - Xm[2][0]*Xm[0][2];
                        float C12 = Xm[2][0]*Xm[0][1] - Xm[2][1]*Xm[0][0];
                        float C20 = Xm[0][1]*Xm[1][2] - Xm[0][2]*Xm[1][1];
                        float C21 = Xm[0][2]*Xm[1][0] - Xm[0][0]*Xm[1][2];
                        float C22 = Xm[0][0]*Xm[1][1] - Xm[0][1]*Xm[1][0];
                        float det = Xm[0][0]*C00 + Xm[0][1]*C01 + Xm[0][2]*C02;
                        if (fabsf(det) < 1e-30f) break;
                        float rd = 0.5f / det;
                        Xm[0][0] = 0.5f*Xm[0][0] + C00*rd; Xm[0][1] = 0.5f*Xm[0][1] + C01*rd; Xm[0][2] = 0.5f*Xm[0][2] + C02*rd;
                        Xm[1][0] = 0.5f*Xm[1][0] + C10*rd; Xm[1][1] = 0.5f*Xm[1][1] + C11*rd; Xm[1][2] = 0.5f*Xm[1][2] + C12*rd;
                        Xm[2][0] = 0.5f*Xm[2][0] + C20*rd; Xm[2][1] = 0.5f*Xm[2][1] + C21*rd; Xm[2][2] = 0.5f*Xm[2][2] + C22*rd;
                    }
                    for (int i = 0; i < 3; i++) for (int j2 = 0; j2 < 3; j2++) R[i][j2] = (double)Xm[j2][i];
                } else {
                    // Jacobi-SVD fallback (deterministic)
                    float A[3][3], V[3][3] = {{1,0,0},{0,1,0},{0,0,1}};
                    for (int i = 0; i < 3; i++)
                        for (int j2 = 0; j2 < 3; j2++)
                            A[i][j2] = H[0][i] * H[0][j2] + H[1][i] * H[1][j2] + H[2][i] * H[2][j2];
                    for (int sweep = 0; sweep < 8; ++sweep) {
                        for (int p = 0; p < 2; p++) for (int q = p + 1; q < 3; q++) {
                            float apq = A[p][q];
                            if (fabsf(apq) < 1e-30f) continue;
                            float theta = (A[q][q] - A[p][p]) / (2.f * apq);
                            float t = copysignf(1.f, theta) / (fabsf(theta) + sqrtf(theta * theta + 1.f));
                            float c = 1.f / sqrtf(t * t + 1.f);
                            float s = t * c;
                            for (int k = 0; k < 3; k++) { float akp = A[k][p], akq = A[k][q]; A[k][p] = c*akp - s*akq; A[k][q] = s*akp + c*akq; }
                            for (int k = 0; k < 3; k++) { float apk = A[p][k], aqk = A[q][k]; A[p][k] = c*apk - s*aqk; A[q][k] = s*apk + c*aqk; }
                            for (int k = 0; k < 3; k++) { float vkp = V[k][p], vkq = V[k][q]; V[k][p] = c*vkp - s*vkq; V[k][q] = s*vkp + c*vkq; }
                        }
                    }
                    float lam[3] = { A[0][0], A[1][1], A[2][2] };
                    int ord[3] = { 0, 1, 2 };
                    if (lam[ord[1]] > lam[ord[0]]) { int t0 = ord[0]; ord[0] = ord[1]; ord[1] = t0; }
                    if (lam[ord[2]] > lam[ord[0]]) { int t0 = ord[0]; ord[0] = ord[2]; ord[2] = t0; }
                    if (lam[ord[2]] > lam[ord[1]]) { int t0 = ord[1]; ord[1] = ord[2]; ord[2] = t0; }
                    float vc[3][3], uc[3][3];
                    for (int i = 0; i < 3; i++) { vc[i][0] = V[0][ord[i]]; vc[i][1] = V[1][ord[i]]; vc[i][2] = V[2][ord[i]]; }
                    for (int i = 0; i < 3; i++) {
                        float u0 = H[0][0]*vc[i][0] + H[0][1]*vc[i][1] + H[0][2]*vc[i][2];
                        float u1 = H[1][0]*vc[i][0] + H[1][1]*vc[i][1] + H[1][2]*vc[i][2];
                        float u2 = H[2][0]*vc[i][0] + H[2][1]*vc[i][1] + H[2][2]*vc[i][2];
                        for (int j2 = 0; j2 < i; j2++) {
                            float dp = u0*uc[j2][0] + u1*uc[j2][1] + u2*uc[j2][2];
                            u0 -= dp*uc[j2][0]; u1 -= dp*uc[j2][1]; u2 -= dp*uc[j2][2];
                        }
                        float nn2 = sqrtf(u0*u0 + u1*u1 + u2*u2);
                        if (nn2 > 1e-12f) { uc[i][0] = u0/nn2; uc[i][1] = u1/nn2; uc[i][2] = u2/nn2; }
                        else if (i == 2) {
                            uc[2][0] = uc[0][1]*uc[1][2] - uc[0][2]*uc[1][1];
                            uc[2][1] = uc[0][2]*uc[1][0] - uc[0][0]*uc[1][2];
                            uc[2][2] = uc[0][0]*uc[1][1] - uc[0][1]*uc[1][0];
                        } else if (i == 1) {
                            float a0 = (fabsf(uc[0][0]) < 0.9f) ? 1.f : 0.f, a1 = 1.f - a0, a2 = 0.f;
                            float dp = a0*uc[0][0] + a1*uc[0][1] + a2*uc[0][2];
                            a0 -= dp*uc[0][0]; a1 -= dp*uc[0][1]; a2 -= dp*uc[0][2];
                            float nn3 = sqrtf(a0*a0 + a1*a1 + a2*a2);
                            uc[1][0] = a0/nn3; uc[1][1] = a1/nn3; uc[1][2] = a2/nn3;
                        } else { uc[0][0] = 1; uc[0][1] = 0; uc[0][2] = 0; }
                    }
                    float detU = uc[0][0]*(uc[1][1]*uc[2][2] - uc[1][2]*uc[2][1])
                               - uc[0][1]*(uc[1][0]*uc[2][2] - uc[1][2]*uc[2][0])
                               + uc[0][2]*(uc[1][0]*uc[2][1] - uc[1][1]*uc[2][0]);
                    float detV = vc[0][0]*(vc[1][1]*vc[2][2] - vc[1][2]*vc[2][1])
                               - vc[0][1]*(vc[1][0]*vc[2][2] - vc[1][2]*vc[2][0])
                               + vc[0][2]*(vc[1][0]*vc[2][1] - vc[1][1]*vc[2][0]);
                    float sgn = (detU * detV < 0.f) ? -1.f : 1.f;
                    for (int i = 0; i < 3; i++)
                        for (int j2 = 0; j2 < 3; j2++)
                            R[i][j2] = (double)(vc[0][i]*uc[0][j2] + vc[1][i]*uc[1][j2] + sgn * vc[2][i]*uc[2][j2]);
                }
                double tr0 = cc0 - (R[0][0]*cs0 + R[0][1]*cs1 + R[0][2]*cs2);
                double tr1 = cc1 - (R[1][0]*cs0 + R[1][1]*cs1 + R[1][2]*cs2);
                double tr2 = cc2 - (R[2][0]*cs0 + R[2][1]*cs1 + R[2][2]*cs2);
                double An[12];
                for (int i = 0; i < 3; i++)
                    for (int j2 = 0; j2 < 3; j2++)
                        An[i*3+j2] = R[i][0]*Td[0*3+j2] + R[i][1]*Td[1*3+j2] + R[i][2]*Td[2*3+j2];
                An[9]  = R[0][0]*Td[9] + R[0][1]*Td[10] + R[0][2]*Td[11] + tr0;
                An[10] = R[1][0]*Td[9] + R[1][1]*Td[10] + R[1][2]*Td[11] + tr1;
                An[11] = R[2][0]*Td[9] + R[2][1]*Td[10] + R[2][2]*Td[11] + tr2;
#pragma unroll
                for (int k = 0; k < 12; k++) {
                    Td[k] = An[k];
                    float tf = (float)An[k];
                    Tsh[k] = tf;
                    st_agent(&Tpub[g * 16 + k], tf);       // publish float T
                }
                st_rel_i(&ctrs[256 + g], iter + 1);        // release: orders T stores
            }
            __syncthreads();
        } else {
            // ---- follower: wait for leader's T ----
            if (tid == 0) {
                while (ld_acq_i(&ctrs[256 + g]) <= iter) __builtin_amdgcn_s_sleep(1);
#pragma unroll
                for (int k = 0; k < 12; k++) Tsh[k] = ld_agent(&Tpub[g * 16 + k]);
            }
            __syncthreads();
        }
    }

    // ---- chamfer phase: aligned into LDS (final T), both directions, last-block loss ----
    {
        float Tf[12];
#pragma unroll
        for (int k = 0; k < 12; k++) Tf[k] = Tsh[k];
        __syncthreads();   // sm_d/sm_i dead; al aliases scratch
        for (int i = tid; i < NPG_; i += 512) {
            const float* q = &tpos[(size_t)(g * NPG_ + i) * 3];
            float X = Tf[0] * q[0] + Tf[1] * q[1] + Tf[2] * q[2] + Tf[9];
            float Y = Tf[3] * q[0] + Tf[4] * q[1] + Tf[5] * q[2] + Tf[10];
            float Z = Tf[6] * q[0] + Tf[7] * q[1] + Tf[8] * q[2] + Tf[11];
            al[swz32(i)] = make_float4(X, Y, Z, fmaf(X, X, fmaf(Y, Y, Z * Z)));
            if (blk == 0) {
                out_aligned[(size_t)(g * NPG_ + i) * 3 + 0] = X;
                out_aligned[(size_t)(g * NPG_ + i) * 3 + 1] = Y;
                out_aligned[(size_t)(g * NPG_ + i) * 3 + 2] = Z;
            }
        }
        __syncthreads();
        float Ax[8], Ay[8], Az[8], Aw[8], Qx[8], Qy[8], Qz[8], Qw[8], d1[8], d2[8];
#pragma unroll
        for (int u = 0; u < 8; u++) {
            int s = swz32(blk * 64 + wave * 8 + u);
            float4 a4 = al[s]; float4 p4 = tq[s];
            Ax[u] = -2.f * a4.x; Ay[u] = -2.f * a4.y; Az[u] = -2.f * a4.z; Aw[u] = a4.w;
            Qx[u] = -2.f * p4.x; Qy[u] = -2.f * p4.y; Qz[u] = -2.f * p4.z; Qw[u] = p4.w;
            d1[u] = 1e30f; d2[u] = 1e30f;
        }
        const int qbase = lane * 32;
        for (int j = 0; j < 32; j++) {
            int s = qbase + (j ^ (lane & 31));
            float4 t4 = tq[s];
            float4 b4 = al[s];
#pragma unroll
            for (int u = 0; u < 8; u++) {
                d1[u] = fminf(d1[u], fmaf(Ax[u], t4.x, fmaf(Ay[u], t4.y, fmaf(Az[u], t4.z, t4.w))));
                d2[u] = fminf(d2[u], fmaf(Qx[u], b4.x, fmaf(Qy[u], b4.y, fmaf(Qz[u], b4.z, b4.w))));
            }
        }
        float s1 = 0.f, s2 = 0.f;
#pragma unroll
        for (int u = 0; u < 8; u++) {
            float a = d1[u], b = d2[u];
            for (int o = 32; o > 0; o >>= 1) {
                a = fminf(a, __shfl_down(a, o));
                b = fminf(b, __shfl_down(b, o));
            }
            s1 += a + Aw[u];     // + |src|^2 completes the squared distance
            s2 += b + Qw[u];
        }
        if (lane == 0) { wred[wave][0] = s1; wred[wave][1] = s2; }
        __syncthreads();
        if (tid == 0) {
            float t1 = 0.f, t2 = 0.f;
#pragma unroll
            for (int w = 0; w < 8; w++) { t1 += wred[w][0]; t2 += wred[w][1]; }
            st_agent(&chpart[blockIdx.x * 2 + 0], t1);
            st_agent(&chpart[blockIdx.x * 2 + 1], t2);
        }
        __syncthreads();
        if (tid == 0) {
            int old = atomicAdd(&ctrs[264], 1);
            lastFlag = (old == (int)gridDim.x - 1) ? 1 : 0;
        }
        __syncthreads();
        if (!lastFlag) return;
        float v1 = 0.f, v2 = 0.f;
        if (tid < 256) {
            v1 = ld_agent(&chpart[tid * 2 + 0]);
            v2 = ld_agent(&chpart[tid * 2 + 1]);
        }
        for (int o = 32; o > 0; o >>= 1) {
            v1 += __shfl_down(v1, o);
            v2 += __shfl_down(v2, o);
        }
        if (lane == 0 && wave < 4) { wred[wave][0] = v1; wred[wave][1] = v2; }
        __syncthreads();
        if (tid == 0) {
            float tot = 0.f;
#pragma unroll
            for (int w = 0; w < 4; w++) tot += wred[w][0] + wred[w][1];
            out_loss[0] = tot / (float)(NPG_ * B_GRAPHS);
        }
    }
}

// ---------------- launcher ----------------
extern "C" void kernel_launch(void* const* d_in, const int* in_sizes, int n_in,
                              void* d_out, int out_size, void* d_ws, size_t ws_size,
                              hipStream_t stream)
{
    (void)in_sizes; (void)n_in; (void)out_size; (void)ws_size;
    const float* x   = (const float*)d_in[0];
    const int*   ei  = (const int*)d_in[1];
    const float* pos = (const float*)d_in[2];
    const float* W1 = (const float*)d_in[4];
    const float* b1 = (const float*)d_in[5];
    const float* W2 = (const float*)d_in[6];
    const float* b2 = (const float*)d_in[7];
    const float* W3 = (const float*)d_in[8];
    const float* b3 = (const float*)d_in[9];
    const float* Wt = (const float*)d_in[10];
    const float* bt = (const float*)d_in[11];
    const int* row = ei;
    const int* col = ei + E_EDGES;

    char* wsb = (char*)d_ws;
    size_t off_b = 0;
    auto alloc = [&](size_t bytes) -> void* {
        void* p = wsb + off_b;
        off_b = (off_b + bytes + 255) & ~(size_t)255;
        return p;
    };
    int*    counts   = (int*)alloc((size_t)N_NODES * 4);
    int*    offs     = (int*)alloc((size_t)(N_NODES + 1) * 4);
    int*    cursor   = (int*)alloc((size_t)N_NODES * 4);
    int*    srcid    = (int*)alloc((size_t)E_EDGES * 4);
    float*  normv    = (float*)alloc((size_t)E_EDGES * 4);
    float*  dinv     = (float*)alloc((size_t)N_NODES * 4);
    unsigned short* xb  = (unsigned short*)alloc((size_t)N_NODES * F_IN * 2);
    unsigned short* W1b = (unsigned short*)alloc((size_t)F_IN * F_HID * 2);
    unsigned short* W2b = (unsigned short*)alloc((size_t)F_HID * F_HID * 2);
    unsigned short* W3b = (unsigned short*)alloc((size_t)F_HID * F_OUT * 2);
    unsigned short* bufA = (unsigned short*)alloc((size_t)N_NODES * F_HID * 2);
    unsigned short* bufB = (unsigned short*)alloc((size_t)N_NODES * F_HID * 2);
    unsigned short* bufC = (unsigned short*)alloc((size_t)N_NODES * F_HID * 2);
    float*  tpos     = (float*)alloc((size_t)N_NODES * 3 * 4);
    float*  partials = (float*)alloc((size_t)256 * 16 * 4);
    float*  Tpub     = (float*)alloc((size_t)B_GRAPHS * 16 * 4);
    int*    ctrs     = (int*)alloc((size_t)512 * 4);
    float*  chpart   = (float*)alloc((size_t)256 * 2 * 4);

    float* out_h       = (float*)d_out;
    float* out_aligned = out_h + (size_t)N_NODES * F_OUT;
    float* out_loss    = out_aligned + (size_t)N_NODES * 3;

    // 1: zero counts (stream-ordered before prep's count phase)
    hipMemsetAsync(counts, 0, (size_t)N_NODES * 4, stream);
    // 2: converts + edge count + ctr zero
    k_prep<<<3585, 256, 0, stream>>>(x, xb, W1, W2, W3, W1b, W2b, W3b, col, counts, ctrs);
    // 3-4: CSR
    k_scan<<<1, 1024, 0, stream>>>(counts, offs, cursor, dinv);
    k_scatter<<<E_EDGES / 256, 256, 0, stream>>>(row, col, cursor, dinv, srcid, normv);

    // 5: layer1 aggregate (x bf16 -> bufA)
    k_agg<F_IN, 0, 0><<<N_NODES / 2, 128, 0, stream>>>(xb, bufA, offs, srcid, normv, dinv,
            nullptr, 0, nullptr, nullptr, nullptr, nullptr);
    // 6: gemm1 + bias + relu
    {
        dim3 grid(F_HID / 64, N_NODES / 128);
        k_gemm_bf16<<<grid, 256, 0, stream>>>(bufA, W1b, b1, bufB, N_NODES, F_HID, F_IN, 1);
    }
    // 7: gemm2 (no bias)
    {
        dim3 grid(F_HID / 64, N_NODES / 128);
        k_gemm_bf16<<<grid, 256, 0, stream>>>(bufB, W2b, nullptr, bufC, N_NODES, F_HID, F_HID, 0);
    }
    // 8: layer2 aggregate + b2 + relu
    k_agg<F_HID, 0, 0><<<N_NODES, 128, 0, stream>>>(bufC, bufA, offs, srcid, normv, dinv,
            b2, 1, nullptr, nullptr, nullptr, nullptr);
    // 9: gemm3
    {
        dim3 grid(F_OUT / 64, N_NODES / 128);
        k_gemm_bf16<<<grid, 256, 0, stream>>>(bufA, W3b, nullptr, bufB, N_NODES, F_OUT, F_HID, 0);
    }
    // 10: layer3 aggregate + b3 -> out_h (fp32), fused tpos
    k_agg<F_OUT, 1, 1><<<N_NODES / 2, 128, 0, stream>>>(bufB, out_h, offs, srcid, normv, dinv,
            b3, 0, Wt, bt, pos, tpos);

    // 11: persistent ICP (10 iterations) + apply + chamfer + loss (256 blocks, 1/CU)
    k_icp_all<<<B_GRAPHS * NN_BPG, 512, 0, stream>>>(tpos, pos, partials, Tpub, chpart, ctrs,
            out_aligned, out_loss);
}

// Round 9
// 373.196 us; speedup vs baseline: 1.1568x; 1.1568x over previous
//
#include <hip/hip_runtime.h>
#include <math.h>

#define N_NODES 16384
#define B_GRAPHS 8
#define NPG_     2048
#define E_EDGES  262144
#define F_IN  128
#define F_HID 256
#define F_OUT 128
#define ICP_IT 10
#define NN_BPG 32   // blocks per graph (64 src pts/block, 512 threads)

typedef __attribute__((ext_vector_type(8))) short bf16x8;
typedef __attribute__((ext_vector_type(4))) float f32x4;

__device__ __forceinline__ float b2f(unsigned short u) {
    union { unsigned int u; float f; } v; v.u = ((unsigned int)u) << 16; return v.f;
}
__device__ __forceinline__ unsigned short f2b(float f) {
    union { float f; unsigned int u; } v; v.f = f;
    unsigned int r = v.u + 0x7FFFu + ((v.u >> 16) & 1u);
    return (unsigned short)(r >> 16);
}
// XOR swizzle within 32-element groups: spreads lane-sliced LDS scans over banks.
__device__ __forceinline__ int swz32(int i) {
    return (i & ~31) | ((i & 31) ^ ((i >> 5) & 31));
}
// Agent-scope accesses (device-coherent; validated R4-R6 pattern).
__device__ __forceinline__ void st_agent(float* p, float v) {
    __hip_atomic_store(p, v, __ATOMIC_RELAXED, __HIP_MEMORY_SCOPE_AGENT);
}
__device__ __forceinline__ float ld_agent(const float* p) {
    return __hip_atomic_load(p, __ATOMIC_RELAXED, __HIP_MEMORY_SCOPE_AGENT);
}
__device__ __forceinline__ int ld_agent_i(const int* p) {
    return __hip_atomic_load(p, __ATOMIC_RELAXED, __HIP_MEMORY_SCOPE_AGENT);
}

// ------- k_prep: x->bf16, weight transpose-converts, edge count (counts pre-zeroed
// by stream-ordered memset), zero sync ctrs ------------------------------------------------
__global__ __launch_bounds__(256) void k_prep(
    const float* __restrict__ x, unsigned short* __restrict__ xb,
    const float* __restrict__ W1, const float* __restrict__ W2, const float* __restrict__ W3,
    unsigned short* __restrict__ W1b, unsigned short* __restrict__ W2b, unsigned short* __restrict__ W3b,
    const int* __restrict__ col, int* __restrict__ counts, int* __restrict__ ctrs)
{
    const int b = blockIdx.x, tid = threadIdx.x;
    if (b < 2048) {                       // x: 524288 float4 -> uint2
        int i = b * 256 + tid;
        float4 v = ((const float4*)x)[i];
        uint2 o;
        o.x = (unsigned int)f2b(v.x) | ((unsigned int)f2b(v.y) << 16);
        o.y = (unsigned int)f2b(v.z) | ((unsigned int)f2b(v.w) << 16);
        ((uint2*)xb)[i] = o;
    } else if (b < 2176) {                // W1 [128][256] -> W1b [256][128]
        int idx = (b - 2048) * 256 + tid;
        int k = idx >> 8, n = idx & 255;
        W1b[n * 128 + k] = f2b(W1[idx]);
    } else if (b < 2432) {                // W2 [256][256] -> W2b [256][256]
        int idx = (b - 2176) * 256 + tid;
        int k = idx >> 8, n = idx & 255;
        W2b[n * 256 + k] = f2b(W2[idx]);
    } else if (b < 2560) {                // W3 [256][128] -> W3b [128][256]
        int idx = (b - 2432) * 256 + tid;
        int k = idx >> 7, n = idx & 127;
        W3b[n * 256 + k] = f2b(W3[idx]);
    } else if (b < 3584) {                // edge in-degree count
        int e = (b - 2560) * 256 + tid;
        atomicAdd(&counts[col[e]], 1);
    } else {                              // zero sync counters (256 ints)
        ctrs[tid] = 0;
    }
}

// ---------------- CSR build ----------------
__global__ __launch_bounds__(1024) void k_scan(const int* __restrict__ counts,
        int* __restrict__ offs, int* __restrict__ cursor, float* __restrict__ dinv)
{
    __shared__ int wtot[16];
    const int t = threadIdx.x;
    const int base = t * 16;
    int local[16];
    int s = 0;
#pragma unroll
    for (int i = 0; i < 16; i++) { local[i] = counts[base + i]; s += local[i]; }
    const int lane = t & 63, w = t >> 6;
    int inc = s;                        // inclusive wave scan
    for (int o = 1; o < 64; o <<= 1) {
        int v = __shfl_up(inc, o);
        if (lane >= o) inc += v;
    }
    if (lane == 63) wtot[w] = inc;
    __syncthreads();
    if (t < 16) {
        int v = wtot[t];
        for (int o = 1; o < 16; o <<= 1) {
            int u = __shfl_up(v, o);
            if (t >= o) v += u;
        }
        wtot[t] = v;
    }
    __syncthreads();
    int run = (w > 0 ? wtot[w - 1] : 0) + (inc - s);
#pragma unroll
    for (int i = 0; i < 16; i++) {
        offs[base + i]   = run;
        cursor[base + i] = run;
        dinv[base + i]   = rsqrtf((float)(local[i] + 1));  // deg = indeg + self loop
        run += local[i];
    }
    if (t == 1023) offs[N_NODES] = run;
}

__global__ void k_scatter(const int* __restrict__ row, const int* __restrict__ col,
        int* __restrict__ cursor, const float* __restrict__ dinv,
        int* __restrict__ srcid, float* __restrict__ normv)
{
    int e = blockIdx.x * 256 + threadIdx.x;
    if (e >= E_EDGES) return;
    int r = row[e], c = col[e];
    int p = atomicAdd(&cursor[c], 1);
    srcid[p] = r;
    normv[p] = dinv[r] * dinv[c];
}

// ---------------- GCN aggregation (bf16 in, fp32 acc); unroll-4 gather; fused tpos --------
template<int W, int OUTF, int FUSET>
__global__ __launch_bounds__(128) void k_agg(const unsigned short* __restrict__ X,
        void* __restrict__ Y,
        const int* __restrict__ offs, const int* __restrict__ srcid,
        const float* __restrict__ normv, const float* __restrict__ dinv,
        const float* __restrict__ bias, int relu,
        const float* __restrict__ Wt, const float* __restrict__ bt,
        const float* __restrict__ pos, float* __restrict__ tposO)
{
    constexpr int NPB = (W == 128) ? 2 : 1;     // nodes per block (128 threads)
    constexpr int W2 = W / 2;
    const int local = (NPB == 2) ? (threadIdx.x >> 6) : 0;
    const int n = blockIdx.x * NPB + local;
    const int j = (NPB == 2) ? (threadIdx.x & 63) : threadIdx.x;
    const unsigned int* Xu = (const unsigned int*)X;
    float di = dinv[n];
    float w0 = di * di;
    unsigned int v = Xu[(size_t)n * W2 + j];
    float a0 = b2f((unsigned short)v) * w0;
    float a1 = b2f((unsigned short)(v >> 16)) * w0;
    int p = offs[n];
    const int p1 = offs[n + 1];
    for (; p + 3 < p1; p += 4) {
        int s0i = srcid[p], s1i = srcid[p + 1], s2i = srcid[p + 2], s3i = srcid[p + 3];
        float n0 = normv[p], n1 = normv[p + 1], n2 = normv[p + 2], n3 = normv[p + 3];
        unsigned int v0 = Xu[(size_t)s0i * W2 + j];
        unsigned int v1 = Xu[(size_t)s1i * W2 + j];
        unsigned int v2 = Xu[(size_t)s2i * W2 + j];
        unsigned int v3 = Xu[(size_t)s3i * W2 + j];
        a0 = fmaf(b2f((unsigned short)v0), n0, a0);
        a1 = fmaf(b2f((unsigned short)(v0 >> 16)), n0, a1);
        a0 = fmaf(b2f((unsigned short)v1), n1, a0);
        a1 = fmaf(b2f((unsigned short)(v1 >> 16)), n1, a1);
        a0 = fmaf(b2f((unsigned short)v2), n2, a0);
        a1 = fmaf(b2f((unsigned short)(v2 >> 16)), n2, a1);
        a0 = fmaf(b2f((unsigned short)v3), n3, a0);
        a1 = fmaf(b2f((unsigned short)(v3 >> 16)), n3, a1);
    }
    for (; p < p1; ++p) {
        unsigned int va = Xu[(size_t)srcid[p] * W2 + j]; float na = normv[p];
        a0 = fmaf(b2f((unsigned short)va), na, a0);
        a1 = fmaf(b2f((unsigned short)(va >> 16)), na, a1);
    }
    if (bias) { a0 += bias[2 * j]; a1 += bias[2 * j + 1]; }
    if (relu) { a0 = fmaxf(a0, 0.f); a1 = fmaxf(a1, 0.f); }
    if (OUTF) {
        float* Yf = (float*)Y;
        Yf[(size_t)n * W + 2 * j]     = a0;
        Yf[(size_t)n * W + 2 * j + 1] = a1;
    } else {
        ((unsigned int*)Y)[(size_t)n * W2 + j] =
            (unsigned int)f2b(a0) | ((unsigned int)f2b(a1) << 16);
    }
    if (FUSET) {   // tpos = pos + h @ Wt + bt, wave-per-node (W==128 only)
        float wt0 = Wt[6 * j + 0], wt1 = Wt[6 * j + 1], wt2 = Wt[6 * j + 2];
        float wt3 = Wt[6 * j + 3], wt4 = Wt[6 * j + 4], wt5 = Wt[6 * j + 5];
        float s0 = a0 * wt0 + a1 * wt3;
        float s1 = a0 * wt1 + a1 * wt4;
        float s2 = a0 * wt2 + a1 * wt5;
        for (int o = 32; o > 0; o >>= 1) {
            s0 += __shfl_down(s0, o);
            s1 += __shfl_down(s1, o);
            s2 += __shfl_down(s2, o);
        }
        if (j == 0) {
            tposO[n * 3 + 0] = pos[n * 3 + 0] + s0 + bt[0];
            tposO[n * 3 + 1] = pos[n * 3 + 1] + s1 + bt[1];
            tposO[n * 3 + 2] = pos[n * 3 + 2] + s2 + bt[2];
        }
    }
}

// ---------------- bf16 MFMA GEMM: C[M,N] = A[M,K] @ Bt[N,K]^T (+bias,relu) ----------------
__global__ __launch_bounds__(256) void k_gemm_bf16(
    const unsigned short* __restrict__ A,   // [M][K] bf16
    const unsigned short* __restrict__ Bt,  // [N][K] bf16
    const float* __restrict__ bias, unsigned short* __restrict__ C,
    int M, int N, int K, int relu)
{
    __shared__ __align__(16) unsigned short As[128 * 64];
    __shared__ __align__(16) unsigned short Bs[64 * 64];
    const int tid  = threadIdx.x;
    const int lane = tid & 63;
    const int wave = tid >> 6;
    const int bm = blockIdx.y * 128, bn = blockIdx.x * 64;
    const int wm = (wave >> 1) * 64, wn = (wave & 1) * 32;
    f32x4 acc[4][2];
#pragma unroll
    for (int mf = 0; mf < 4; mf++)
#pragma unroll
        for (int nf = 0; nf < 2; nf++) acc[mf][nf] = (f32x4){0.f, 0.f, 0.f, 0.f};

    for (int k0 = 0; k0 < K; k0 += 64) {
#pragma unroll
        for (int i = 0; i < 4; i++) {
            int idx = i * 256 + tid;
            int m = idx >> 3, slot = idx & 7;
            const unsigned short* src = A + (size_t)(bm + m) * K + k0 + ((slot ^ (m & 7)) << 3);
            __builtin_amdgcn_global_load_lds(
                (const __attribute__((address_space(1))) unsigned int*)src,
                (__attribute__((address_space(3))) unsigned int*)(As + (size_t)i * 2048 + wave * 512),
                16, 0, 0);
        }
#pragma unroll
        for (int i = 0; i < 2; i++) {
            int idx = i * 256 + tid;
            int n = idx >> 3, slot = idx & 7;
            const unsigned short* src = Bt + (size_t)(bn + n) * K + k0 + ((slot ^ (n & 7)) << 3);
            __builtin_amdgcn_global_load_lds(
                (const __attribute__((address_space(1))) unsigned int*)src,
                (__attribute__((address_space(3))) unsigned int*)(Bs + (size_t)i * 2048 + wave * 512),
                16, 0, 0);
        }
        __syncthreads();
        bf16x8 af[4][2], bfr[2][2];
        const int qd = lane >> 4;
#pragma unroll
        for (int s = 0; s < 2; s++) {
#pragma unroll
            for (int mf = 0; mf < 4; mf++) {
                int m = wm + mf * 16 + (lane & 15);
                int slot = (s * 4 + qd) ^ (m & 7);
                af[mf][s] = *(const bf16x8*)(As + m * 64 + slot * 8);
            }
#pragma unroll
            for (int nf = 0; nf < 2; nf++) {
                int n = wn + nf * 16 + (lane & 15);
                int slot = (s * 4 + qd) ^ (n & 7);
                bfr[nf][s] = *(const bf16x8*)(Bs + n * 64 + slot * 8);
            }
        }
#pragma unroll
        for (int s = 0; s < 2; s++)
#pragma unroll
            for (int mf = 0; mf < 4; mf++)
#pragma unroll
                for (int nf = 0; nf < 2; nf++)
                    acc[mf][nf] = __builtin_amdgcn_mfma_f32_16x16x32_bf16(
                        af[mf][s], bfr[nf][s], acc[mf][nf], 0, 0, 0);
        __syncthreads();
    }
#pragma unroll
    for (int nf = 0; nf < 2; nf++) {
        int col = bn + wn + nf * 16 + (lane & 15);
        float bv = bias ? bias[col] : 0.f;
#pragma unroll
        for (int mf = 0; mf < 4; mf++) {
#pragma unroll
            for (int r = 0; r < 4; r++) {
                int row = bm + wm + mf * 16 + (lane >> 4) * 4 + r;
                float v = acc[mf][nf][r] + bv;
                if (relu) v = fmaxf(v, 0.f);
                C[(size_t)row * N + col] = f2b(v);
            }
        }
    }
}

// ---------------- persistent ICP (10 iters) + chamfer + loss, ONE launch ------------------
// R6 structure (256 blocks x 512 thr, per-graph ctr, redundant parallel gather+SVD = ONE
// global handoff leg/iter). NEW: partials exchanged via release/acquire fence protocol --
// plain stores + __threadfence before arrival; after detect, one __threadfence then 128
// coalesced cached float4 loads (kills the 123K-request uncached gather storm of R6).
__global__ __launch_bounds__(512) void k_icp_all(
    const float* __restrict__ tpos, const float* __restrict__ pos,
    float* __restrict__ partials,   // [2][256][16]
    float* __restrict__ chpart,     // [256][2]
    int* __restrict__ ctrs,         // [g*16]=per-graph iter arrivals, [128]=chamfer
    float* __restrict__ out_aligned, float* __restrict__ out_loss)
{
    const int g = blockIdx.x >> 5, blk = blockIdx.x & 31;
    const int tid = threadIdx.x;
    const int wave = tid >> 6, lane = tid & 63;
    __shared__ float4 tq[NPG_];                                // 32KB, swizzled, w=|t|^2
    __shared__ __align__(16) unsigned char scratch[NPG_ * 16]; // 32KB union (sm_d/sm_i | al)
    float* sm_d = (float*)scratch;                             // [64][65]
    unsigned short* sm_i = (unsigned short*)(scratch + 64 * 65 * 4);
    float4* al = (float4*)scratch;                             // chamfer phase only
    __shared__ __align__(16) float pmom[32][16];               // gathered graph partials
    __shared__ float ssx[64], ssy[64], ssz[64];
    __shared__ float wred[8][2];
    __shared__ float Tsh[12];
    __shared__ double sdl[15];
    __shared__ int lastFlag;

    for (int i = tid; i < NPG_; i += 512) {
        const float* p = &pos[(size_t)(g * NPG_ + i) * 3];
        float qx = p[0], qy = p[1], qz = p[2];
        tq[swz32(i)] = make_float4(qx, qy, qz, fmaf(qx, qx, fmaf(qy, qy, qz * qz)));
    }
    if (tid < 12) Tsh[tid] = (tid == 0 || tid == 4 || tid == 8) ? 1.f : 0.f;
    // own 64 source points (8 per wave) in registers for all 10 iterations
    float Px[8], Py[8], Pz[8];
#pragma unroll
    for (int u = 0; u < 8; u++) {
        int n = g * NPG_ + blk * 64 + wave * 8 + u;
        Px[u] = tpos[n * 3 + 0]; Py[u] = tpos[n * 3 + 1]; Pz[u] = tpos[n * 3 + 2];
    }
    double Td[12];
    if (tid == 0) {
#pragma unroll
        for (int k = 0; k < 12; k++) Td[k] = (k == 0 || k == 4 || k == 8) ? 1.0 : 0.0;
    }
    __syncthreads();

    for (int iter = 0; iter < ICP_IT; ++iter) {
        const int bufbase = (iter & 1) * 256;
        float Tf[12];
#pragma unroll
        for (int k = 0; k < 12; k++) Tf[k] = Tsh[k];
        float Sx[8], Sy[8], Sz[8], Tx[8], Ty[8], Tz[8], bd[8];
        int bi[8];
#pragma unroll
        for (int u = 0; u < 8; u++) {
            float X = Tf[0] * Px[u] + Tf[1] * Py[u] + Tf[2] * Pz[u] + Tf[9];
            float Y = Tf[3] * Px[u] + Tf[4] * Py[u] + Tf[5] * Pz[u] + Tf[10];
            float Z = Tf[6] * Px[u] + Tf[7] * Py[u] + Tf[8] * Pz[u] + Tf[11];
            Sx[u] = X; Sy[u] = Y; Sz[u] = Z;
            Tx[u] = -2.f * X; Ty[u] = -2.f * Y; Tz[u] = -2.f * Z;
            bd[u] = 1e30f; bi[u] = lane * 32;
        }
        const int qbase = lane * 32;
        for (int j = 0; j < 32; j++) {
            float4 t4 = tq[qbase + (j ^ (lane & 31))];
            int idx = qbase + j;
#pragma unroll
            for (int u = 0; u < 8; u++) {
                // d' = |t|^2 - 2 s.t  (monotone in true distance)
                float d = fmaf(Tx[u], t4.x, fmaf(Ty[u], t4.y, fmaf(Tz[u], t4.z, t4.w)));
                if (d < bd[u]) { bd[u] = d; bi[u] = idx; }
            }
        }
        // stage candidates + transformed src coords
#pragma unroll
        for (int u = 0; u < 8; u++) {
            int row = wave * 8 + u;
            sm_d[row * 65 + lane] = bd[u];
            sm_i[row * 65 + lane] = (unsigned short)bi[u];
            if (lane == u) { ssx[row] = Sx[u]; ssy[row] = Sy[u]; ssz[row] = Sz[u]; }
        }
        __syncthreads();
        // wave 0: per-src argmin over 64 lane-slices (ranges ascend -> strict < = first idx),
        // then 15 block-moment shuffle sums; lane 0 writes partial row (plain stores).
        if (tid < 64) {
            const int s = tid;
            float best = sm_d[s * 65];
            int ib = sm_i[s * 65];
            for (int r = 1; r < 64; r++) {
                float dd = sm_d[s * 65 + r];
                int ii = sm_i[s * 65 + r];
                if (dd < best) { best = dd; ib = ii; }
            }
            float4 c = tq[swz32(ib)];
            float X = ssx[s], Y = ssy[s], Z = ssz[s];
            float vals[15] = { X, Y, Z, c.x, c.y, c.z,
                               X * c.x, X * c.y, X * c.z,
                               Y * c.x, Y * c.y, Y * c.z,
                               Z * c.x, Z * c.y, Z * c.z };
#pragma unroll
            for (int k = 0; k < 15; k++) {
                float v = vals[k];
                for (int o = 32; o > 0; o >>= 1) v += __shfl_down(v, o);
                if (tid == 0) partials[((size_t)bufbase + blockIdx.x) * 16 + k] = v;
            }
        }
        __syncthreads();
        if (tid == 0) {
            __threadfence();                              // release: flush partials to LLC
            atomicAdd(&ctrs[g * 16], 1);
            const int target = 32 * (iter + 1);
            while (ld_agent_i(&ctrs[g * 16]) < target) __builtin_amdgcn_s_sleep(2);
            __threadfence();                              // acquire: invalidate L1/L2
        }
        __syncthreads();
        // coalesced cached gather: the graph's 32x16-float partial block (2KB)
        if (tid < 128) {
            const float4* src = (const float4*)(partials + ((size_t)bufbase + g * 32) * 16);
            ((float4*)pmom)[tid] = src[tid];
        }
        __syncthreads();
        if (tid < 15) {
            double acc = 0;
            for (int b = 0; b < NN_BPG; b++) acc += (double)pmom[b][tid];
            sdl[tid] = acc;
        }
        __syncthreads();
        if (tid == 0) {
            double sd[15];
#pragma unroll
            for (int k = 0; k < 15; k++) sd[k] = sdl[k];
            const double n = (double)NPG_;
            const double rin = 1.0 / (double)NPG_;
            double cs0 = sd[0] * rin, cs1 = sd[1] * rin, cs2 = sd[2] * rin;
            double cc0 = sd[3] * rin, cc1 = sd[4] * rin, cc2 = sd[5] * rin;
            float H[3][3];
            H[0][0] = (float)(sd[6]  - n * cs0 * cc0); H[0][1] = (float)(sd[7]  - n * cs0 * cc1); H[0][2] = (float)(sd[8]  - n * cs0 * cc2);
            H[1][0] = (float)(sd[9]  - n * cs1 * cc0); H[1][1] = (float)(sd[10] - n * cs1 * cc1); H[1][2] = (float)(sd[11] - n * cs1 * cc2);
            H[2][0] = (float)(sd[12] - n * cs2 * cc0); H[2][1] = (float)(sd[13] - n * cs2 * cc1); H[2][2] = (float)(sd[14] - n * cs2 * cc2);
            double R[3][3];
            float fn = 1e-30f;
            for (int i = 0; i < 3; i++) for (int j2 = 0; j2 < 3; j2++) fn += H[i][j2] * H[i][j2];
            float sc = rsqrtf(fn);
            float Xm[3][3];
            for (int i = 0; i < 3; i++) for (int j2 = 0; j2 < 3; j2++) Xm[i][j2] = H[i][j2] * sc;
            float dX = Xm[0][0] * (Xm[1][1]*Xm[2][2] - Xm[1][2]*Xm[2][1])
                     - Xm[0][1] * (Xm[1][0]*Xm[2][2] - Xm[1][2]*Xm[2][0])
                     + Xm[0][2] * (Xm[1][0]*Xm[2][1] - Xm[1][1]*Xm[2][0]);
            if (dX > 1e-4f) {
                // polar Newton: X <- 0.5*(X + cof(X)/det(X)); R_ref = Q^T
                for (int itn = 0; itn < 16; ++itn) {
                    float C00 = Xm[1][1]*Xm[2][2] - Xm[1][2]*Xm[2][1];
                    float C01 = Xm[1][2]*Xm[2][0] - Xm[1][0]*Xm[2][2];
                    float C02 = Xm[1][0]*Xm[2][1] - Xm[1][1]*Xm[2][0];
                    float C10 = Xm[2][1]*Xm[0][2] - Xm[2][2]*Xm[0][1];
                    float C11 = Xm[2][2]*Xm[0][0] - Xm[2][0]*Xm[0][2];
                    float C12 = Xm[2][0]*Xm[0][1] - Xm[2][1]*Xm[0][0];
                    float C20 = Xm[0][1]*Xm[1][2] - Xm[0][2]*Xm[1][1];
                    float C21 = Xm[0][2]*Xm[1][0] - Xm[0][0]*Xm[1][2];
                    float C22 = Xm[0][0]*Xm[1][1] - Xm[0][1]*Xm[1][0];
                    float det = Xm[0][0]*C00 + Xm[0][1]*C01 + Xm[0][2]*C02;
                    if (fabsf(det) < 1e-30f) break;
                    float rd = 0.5f / det;
                    Xm[0][0] = 0.5f*Xm[0][0] + C00*rd; Xm[0][1] = 0.5f*Xm[0][1] + C01*rd; Xm[0][2] = 0.5f*Xm[0][2] + C02*rd;
                    Xm[1][0] = 0.5f*Xm[1][0] + C10*rd; Xm[1][1] = 0.5f*Xm[1][1] + C11*rd; Xm[1][2] = 0.5f*Xm[1][2] + C12*rd;
                    Xm[2][0] = 0.5f*Xm[2][0] + C20*rd; Xm[2][1] = 0.5f*Xm[2][1] + C21*rd; Xm[2][2] = 0.5f*Xm[2][2] + C22*rd;
                }
                for (int i = 0; i < 3; i++) for (int j2 = 0; j2 < 3; j2++) R[i][j2] = (double)Xm[j2][i];
            } else {
                // Jacobi-SVD fallback (deterministic)
                float A[3][3], V[3][3] = {{1,0,0},{0,1,0},{0,0,1}};
                for (int i = 0; i < 3; i++)
                    for (int j2 = 0; j2 < 3; j2++)
                        A[i][j2] = H[0][i] * H[0][j2] + H[1][i] * H[1][j2] + H[2][i] * H[2][j2];
                for (int sweep = 0; sweep < 8; ++sweep) {
                    for (int p = 0; p < 2; p++) for (int q = p + 1; q < 3; q++) {
                        float apq = A[p][q];
                        if (fabsf(apq) < 1e-30f) continue;
                        float theta = (A[q][q] - A[p][p]) / (2.f * apq);
                        float t = copysignf(1.f, theta) / (fabsf(theta) + sqrtf(theta * theta + 1.f));
                        float c = 1.f / sqrtf(t * t + 1.f);
                        float s = t * c;
                        for (int k = 0; k < 3; k++) { float akp = A[k][p], akq = A[k][q]; A[k][p] = c*akp - s*akq; A[k][q] = s*akp + c*akq; }
                        for (int k = 0; k < 3; k++) { float apk = A[p][k], aqk = A[q][k]; A[p][k] = c*apk - s*aqk; A[q][k] = s*apk + c*aqk; }
                        for (int k = 0; k < 3; k++) { float vkp = V[k][p], vkq = V[k][q]; V[k][p] = c*vkp - s*vkq; V[k][q] = s*vkp + c*vkq; }
                    }
                }
                float lam[3] = { A[0][0], A[1][1], A[2][2] };
                int ord[3] = { 0, 1, 2 };
                if (lam[ord[1]] > lam[ord[0]]) { int t0 = ord[0]; ord[0] = ord[1]; ord[1] = t0; }
                if (lam[ord[2]] > lam[ord[0]]) { int t0 = ord[0]; ord[0] = ord[2]; ord[2] = t0; }
                if (lam[ord[2]] > lam[ord[1]]) { int t0 = ord[1]; ord[1] = ord[2]; ord[2] = t0; }
                float vc[3][3], uc[3][3];
                for (int i = 0; i < 3; i++) { vc[i][0] = V[0][ord[i]]; vc[i][1] = V[1][ord[i]]; vc[i][2] = V[2][ord[i]]; }
                for (int i = 0; i < 3; i++) {
                    float u0 = H[0][0]*vc[i][0] + H[0][1]*vc[i][1] + H[0][2]*vc[i][2];
                    float u1 = H[1][0]*vc[i][0] + H[1][1]*vc[i][1] + H[1][2]*vc[i][2];
                    float u2 = H[2][0]*vc[i][0] + H[2][1]*vc[i][1] + H[2][2]*vc[i][2];
                    for (int j2 = 0; j2 < i; j2++) {
                        float dp = u0*uc[j2][0] + u1*uc[j2][1] + u2*uc[j2][2];
                        u0 -= dp*uc[j2][0]; u1 -= dp*uc[j2][1]; u2 -= dp*uc[j2][2];
                    }
                    float nn2 = sqrtf(u0*u0 + u1*u1 + u2*u2);
                    if (nn2 > 1e-12f) { uc[i][0] = u0/nn2; uc[i][1] = u1/nn2; uc[i][2] = u2/nn2; }
                    else if (i == 2) {
                        uc[2][0] = uc[0][1]*uc[1][2] - uc[0][2]*uc[1][1];
                        uc[2][1] = uc[0][2]*uc[1][0] - uc[0][0]*uc[1][2];
                        uc[2][2] = uc[0][0]*uc[1][1] - uc[0][1]*uc[1][0];
                    } else if (i == 1) {
                        float a0 = (fabsf(uc[0][0]) < 0.9f) ? 1.f : 0.f, a1 = 1.f - a0, a2 = 0.f;
                        float dp = a0*uc[0][0] + a1*uc[0][1] + a2*uc[0][2];
                        a0 -= dp*uc[0][0]; a1 -= dp*uc[0][1]; a2 -= dp*uc[0][2];
                        float nn3 = sqrtf(a0*a0 + a1*a1 + a2*a2);
                        uc[1][0] = a0/nn3; uc[1][1] = a1/nn3; uc[1][2] = a2/nn3;
                    } else { uc[0][0] = 1; uc[0][1] = 0; uc[0][2] = 0; }
                }
                float detU = uc[0][0]*(uc[1][1]*uc[2][2] - uc[1][2]*uc[2][1])
                           - uc[0][1]*(uc[1][0]*uc[2][2] - uc[1][2]*uc[2][0])
                           + uc[0][2]*(uc[1][0]*uc[2][1] - uc[1][1]*uc[2][0]);
                float detV = vc[0][0]*(vc[1][1]*vc[2][2] - vc[1][2]*vc[2][1])
                           - vc[0][1]*(vc[1][0]*vc[2][2] - vc[1][2]*vc[2][0])
                           + vc[0][2]*(vc[1][0]*vc[2][1] - vc[1][1]*vc[2][0]);
                float sgn = (detU * detV < 0.f) ? -1.f : 1.f;
                for (int i = 0; i < 3; i++)
                    for (int j2 = 0; j2 < 3; j2++)
                        R[i][j2] = (double)(vc[0][i]*uc[0][j2] + vc[1][i]*uc[1][j2] + sgn * vc[2][i]*uc[2][j2]);
            }
            double tr0 = cc0 - (R[0][0]*cs0 + R[0][1]*cs1 + R[0][2]*cs2);
            double tr1 = cc1 - (R[1][0]*cs0 + R[1][1]*cs1 + R[1][2]*cs2);
            double tr2 = cc2 - (R[2][0]*cs0 + R[2][1]*cs1 + R[2][2]*cs2);
            double An[12];
            for (int i = 0; i < 3; i++)
                for (int j2 = 0; j2 < 3; j2++)
                    An[i*3+j2] = R[i][0]*Td[0*3+j2] + R[i][1]*Td[1*3+j2] + R[i][2]*Td[2*3+j2];
            An[9]  = R[0][0]*Td[9] + R[0][1]*Td[10] + R[0][2]*Td[11] + tr0;
            An[10] = R[1][0]*Td[9] + R[1][1]*Td[10] + R[1][2]*Td[11] + tr1;
            An[11] = R[2][0]*Td[9] + R[2][1]*Td[10] + R[2][2]*Td[11] + tr2;
#pragma unroll
            for (int k = 0; k < 12; k++) { Td[k] = An[k]; Tsh[k] = (float)An[k]; }
        }
        __syncthreads();
    }

    // ---- chamfer phase: aligned into LDS (final T), both directions, last-block loss ----
    {
        float Tf[12];
#pragma unroll
        for (int k = 0; k < 12; k++) Tf[k] = Tsh[k];
        __syncthreads();   // sm_d/sm_i dead; al aliases scratch
        for (int i = tid; i < NPG_; i += 512) {
            const float* q = &tpos[(size_t)(g * NPG_ + i) * 3];
            float X = Tf[0] * q[0] + Tf[1] * q[1] + Tf[2] * q[2] + Tf[9];
            float Y = Tf[3] * q[0] + Tf[4] * q[1] + Tf[5] * q[2] + Tf[10];
            float Z = Tf[6] * q[0] + Tf[7] * q[1] + Tf[8] * q[2] + Tf[11];
            al[swz32(i)] = make_float4(X, Y, Z, fmaf(X, X, fmaf(Y, Y, Z * Z)));
            if (blk == 0) {
                out_aligned[(size_t)(g * NPG_ + i) * 3 + 0] = X;
                out_aligned[(size_t)(g * NPG_ + i) * 3 + 1] = Y;
                out_aligned[(size_t)(g * NPG_ + i) * 3 + 2] = Z;
            }
        }
        __syncthreads();
        float Ax[8], Ay[8], Az[8], Aw[8], Qx[8], Qy[8], Qz[8], Qw[8], d1[8], d2[8];
#pragma unroll
        for (int u = 0; u < 8; u++) {
            int s = swz32(blk * 64 + wave * 8 + u);
            float4 a4 = al[s]; float4 p4 = tq[s];
            Ax[u] = -2.f * a4.x; Ay[u] = -2.f * a4.y; Az[u] = -2.f * a4.z; Aw[u] = a4.w;
            Qx[u] = -2.f * p4.x; Qy[u] = -2.f * p4.y; Qz[u] = -2.f * p4.z; Qw[u] = p4.w;
            d1[u] = 1e30f; d2[u] = 1e30f;
        }
        const int qbase = lane * 32;
        for (int j = 0; j < 32; j++) {
            int s = qbase + (j ^ (lane & 31));
            float4 t4 = tq[s];
            float4 b4 = al[s];
#pragma unroll
            for (int u = 0; u < 8; u++) {
                d1[u] = fminf(d1[u], fmaf(Ax[u], t4.x, fmaf(Ay[u], t4.y, fmaf(Az[u], t4.z, t4.w))));
                d2[u] = fminf(d2[u], fmaf(Qx[u], b4.x, fmaf(Qy[u], b4.y, fmaf(Qz[u], b4.z, b4.w))));
            }
        }
        float s1 = 0.f, s2 = 0.f;
#pragma unroll
        for (int u = 0; u < 8; u++) {
            float a = d1[u], b = d2[u];
            for (int o = 32; o > 0; o >>= 1) {
                a = fminf(a, __shfl_down(a, o));
                b = fminf(b, __shfl_down(b, o));
            }
            s1 += a + Aw[u];     // + |src|^2 completes the squared distance
            s2 += b + Qw[u];
        }
        if (lane == 0) { wred[wave][0] = s1; wred[wave][1] = s2; }
        __syncthreads();
        if (tid == 0) {
            float t1 = 0.f, t2 = 0.f;
#pragma unroll
            for (int w = 0; w < 8; w++) { t1 += wred[w][0]; t2 += wred[w][1]; }
            st_agent(&chpart[blockIdx.x * 2 + 0], t1);
            st_agent(&chpart[blockIdx.x * 2 + 1], t2);
        }
        __syncthreads();
        if (tid == 0) {
            int old = atomicAdd(&ctrs[128], 1);
            lastFlag = (old == (int)gridDim.x - 1) ? 1 : 0;
        }
        __syncthreads();
        if (!lastFlag) return;
        float v1 = 0.f, v2 = 0.f;
        if (tid < 256) {
            v1 = ld_agent(&chpart[tid * 2 + 0]);
            v2 = ld_agent(&chpart[tid * 2 + 1]);
        }
        for (int o = 32; o > 0; o >>= 1) {
            v1 += __shfl_down(v1, o);
            v2 += __shfl_down(v2, o);
        }
        if (lane == 0 && wave < 4) { wred[wave][0] = v1; wred[wave][1] = v2; }
        __syncthreads();
        if (tid == 0) {
            float tot = 0.f;
#pragma unroll
            for (int w = 0; w < 4; w++) tot += wred[w][0] + wred[w][1];
            out_loss[0] = tot / (float)(NPG_ * B_GRAPHS);
        }
    }
}

// ---------------- launcher ----------------
extern "C" void kernel_launch(void* const* d_in, const int* in_sizes, int n_in,
                              void* d_out, int out_size, void* d_ws, size_t ws_size,
                              hipStream_t stream)
{
    (void)in_sizes; (void)n_in; (void)out_size; (void)ws_size;
    const float* x   = (const float*)d_in[0];
    const int*   ei  = (const int*)d_in[1];
    const float* pos = (const float*)d_in[2];
    const float* W1 = (const float*)d_in[4];
    const float* b1 = (const float*)d_in[5];
    const float* W2 = (const float*)d_in[6];
    const float* b2 = (const float*)d_in[7];
    const float* W3 = (const float*)d_in[8];
    const float* b3 = (const float*)d_in[9];
    const float* Wt = (const float*)d_in[10];
    const float* bt = (const float*)d_in[11];
    const int* row = ei;
    const int* col = ei + E_EDGES;

    char* wsb = (char*)d_ws;
    size_t off_b = 0;
    auto alloc = [&](size_t bytes) -> void* {
        void* p = wsb + off_b;
        off_b = (off_b + bytes + 255) & ~(size_t)255;
        return p;
    };
    int*    counts   = (int*)alloc((size_t)N_NODES * 4);
    int*    offs     = (int*)alloc((size_t)(N_NODES + 1) * 4);
    int*    cursor   = (int*)alloc((size_t)N_NODES * 4);
    int*    srcid    = (int*)alloc((size_t)E_EDGES * 4);
    float*  normv    = (float*)alloc((size_t)E_EDGES * 4);
    float*  dinv     = (float*)alloc((size_t)N_NODES * 4);
    unsigned short* xb  = (unsigned short*)alloc((size_t)N_NODES * F_IN * 2);
    unsigned short* W1b = (unsigned short*)alloc((size_t)F_IN * F_HID * 2);
    unsigned short* W2b = (unsigned short*)alloc((size_t)F_HID * F_HID * 2);
    unsigned short* W3b = (unsigned short*)alloc((size_t)F_HID * F_OUT * 2);
    unsigned short* bufA = (unsigned short*)alloc((size_t)N_NODES * F_HID * 2);
    unsigned short* bufB = (unsigned short*)alloc((size_t)N_NODES * F_HID * 2);
    unsigned short* bufC = (unsigned short*)alloc((size_t)N_NODES * F_HID * 2);
    float*  tpos     = (float*)alloc((size_t)N_NODES * 3 * 4);
    float*  partials = (float*)alloc((size_t)2 * 256 * 16 * 4);
    int*    ctrs     = (int*)alloc((size_t)256 * 4);
    float*  chpart   = (float*)alloc((size_t)256 * 2 * 4);

    float* out_h       = (float*)d_out;
    float* out_aligned = out_h + (size_t)N_NODES * F_OUT;
    float* out_loss    = out_aligned + (size_t)N_NODES * 3;

    // 1: zero counts (stream-ordered before prep's count phase)
    hipMemsetAsync(counts, 0, (size_t)N_NODES * 4, stream);
    // 2: converts + edge count + ctr zero
    k_prep<<<3585, 256, 0, stream>>>(x, xb, W1, W2, W3, W1b, W2b, W3b, col, counts, ctrs);
    // 3-4: CSR
    k_scan<<<1, 1024, 0, stream>>>(counts, offs, cursor, dinv);
    k_scatter<<<E_EDGES / 256, 256, 0, stream>>>(row, col, cursor, dinv, srcid, normv);

    // 5: layer1 aggregate (x bf16 -> bufA)
    k_agg<F_IN, 0, 0><<<N_NODES / 2, 128, 0, stream>>>(xb, bufA, offs, srcid, normv, dinv,
            nullptr, 0, nullptr, nullptr, nullptr, nullptr);
    // 6: gemm1 + bias + relu
    {
        dim3 grid(F_HID / 64, N_NODES / 128);
        k_gemm_bf16<<<grid, 256, 0, stream>>>(bufA, W1b, b1, bufB, N_NODES, F_HID, F_IN, 1);
    }
    // 7: gemm2 (no bias)
    {
        dim3 grid(F_HID / 64, N_NODES / 128);
        k_gemm_bf16<<<grid, 256, 0, stream>>>(bufB, W2b, nullptr, bufC, N_NODES, F_HID, F_HID, 0);
    }
    // 8: layer2 aggregate + b2 + relu
    k_agg<F_HID, 0, 0><<<N_NODES, 128, 0, stream>>>(bufC, bufA, offs, srcid, normv, dinv,
            b2, 1, nullptr, nullptr, nullptr, nullptr);
    // 9: gemm3
    {
        dim3 grid(F_OUT / 64, N_NODES / 128);
        k_gemm_bf16<<<grid, 256, 0, stream>>>(bufA, W3b, nullptr, bufB, N_NODES, F_OUT, F_HID, 0);
    }
    // 10: layer3 aggregate + b3 -> out_h (fp32), fused tpos
    k_agg<F_OUT, 1, 1><<<N_NODES / 2, 128, 0, stream>>>(bufB, out_h, offs, srcid, normv, dinv,
            b3, 0, Wt, bt, pos, tpos);

    // 11: persistent ICP (10 iterations) + apply + chamfer + loss (256 blocks, 1/CU)
    k_icp_all<<<B_GRAPHS * NN_BPG, 512, 0, stream>>>(tpos, pos, partials, chpart, ctrs,
            out_aligned, out_loss);
}

// Round 10
// 308.800 us; speedup vs baseline: 1.3980x; 1.2085x over previous
//
#include <hip/hip_runtime.h>
#include <math.h>

#define N_NODES 16384
#define B_GRAPHS 8
#define NPG_     2048
#define E_EDGES  262144
#define F_IN  128
#define F_HID 256
#define F_OUT 128
#define ICP_IT 10
#define NN_BPG 32   // blocks per graph (64 src pts/block, 512 threads)

typedef __attribute__((ext_vector_type(8))) short bf16x8;
typedef __attribute__((ext_vector_type(4))) float f32x4;

__device__ __forceinline__ float b2f(unsigned short u) {
    union { unsigned int u; float f; } v; v.u = ((unsigned int)u) << 16; return v.f;
}
__device__ __forceinline__ unsigned short f2b(float f) {
    union { float f; unsigned int u; } v; v.f = f;
    unsigned int r = v.u + 0x7FFFu + ((v.u >> 16) & 1u);
    return (unsigned short)(r >> 16);
}
// XOR swizzle within 32-element groups: spreads lane-sliced LDS scans over banks.
__device__ __forceinline__ int swz32(int i) {
    return (i & ~31) | ((i & 31) ^ ((i >> 5) & 31));
}
// Agent-scope accesses (device-coherent; validated R4-R6 pattern).
__device__ __forceinline__ void st_agent(float* p, float v) {
    __hip_atomic_store(p, v, __ATOMIC_RELAXED, __HIP_MEMORY_SCOPE_AGENT);
}
__device__ __forceinline__ float ld_agent(const float* p) {
    return __hip_atomic_load(p, __ATOMIC_RELAXED, __HIP_MEMORY_SCOPE_AGENT);
}
__device__ __forceinline__ void st_agent_i(int* p, int v) {
    __hip_atomic_store(p, v, __ATOMIC_RELAXED, __HIP_MEMORY_SCOPE_AGENT);
}
__device__ __forceinline__ int ld_agent_i(const int* p) {
    return __hip_atomic_load(p, __ATOMIC_RELAXED, __HIP_MEMORY_SCOPE_AGENT);
}

// ------- k_prep: x->bf16, weight transpose-converts, edge count (counts/partials/ctrs
// pre-zeroed by one stream-ordered memset) -------------------------------------------------
__global__ __launch_bounds__(256) void k_prep(
    const float* __restrict__ x, unsigned short* __restrict__ xb,
    const float* __restrict__ W1, const float* __restrict__ W2, const float* __restrict__ W3,
    unsigned short* __restrict__ W1b, unsigned short* __restrict__ W2b, unsigned short* __restrict__ W3b,
    const int* __restrict__ col, int* __restrict__ counts)
{
    const int b = blockIdx.x, tid = threadIdx.x;
    if (b < 2048) {                       // x: 524288 float4 -> uint2
        int i = b * 256 + tid;
        float4 v = ((const float4*)x)[i];
        uint2 o;
        o.x = (unsigned int)f2b(v.x) | ((unsigned int)f2b(v.y) << 16);
        o.y = (unsigned int)f2b(v.z) | ((unsigned int)f2b(v.w) << 16);
        ((uint2*)xb)[i] = o;
    } else if (b < 2176) {                // W1 [128][256] -> W1b [256][128]
        int idx = (b - 2048) * 256 + tid;
        int k = idx >> 8, n = idx & 255;
        W1b[n * 128 + k] = f2b(W1[idx]);
    } else if (b < 2432) {                // W2 [256][256] -> W2b [256][256]
        int idx = (b - 2176) * 256 + tid;
        int k = idx >> 8, n = idx & 255;
        W2b[n * 256 + k] = f2b(W2[idx]);
    } else if (b < 2560) {                // W3 [256][128] -> W3b [128][256]
        int idx = (b - 2432) * 256 + tid;
        int k = idx >> 7, n = idx & 127;
        W3b[n * 256 + k] = f2b(W3[idx]);
    } else {                              // edge in-degree count
        int e = (b - 2560) * 256 + tid;
        atomicAdd(&counts[col[e]], 1);
    }
}

// ---------------- CSR build ----------------
__global__ __launch_bounds__(1024) void k_scan(const int* __restrict__ counts,
        int* __restrict__ offs, int* __restrict__ cursor, float* __restrict__ dinv)
{
    __shared__ int wtot[16];
    const int t = threadIdx.x;
    const int base = t * 16;
    int local[16];
    int s = 0;
#pragma unroll
    for (int i = 0; i < 16; i++) { local[i] = counts[base + i]; s += local[i]; }
    const int lane = t & 63, w = t >> 6;
    int inc = s;                        // inclusive wave scan
    for (int o = 1; o < 64; o <<= 1) {
        int v = __shfl_up(inc, o);
        if (lane >= o) inc += v;
    }
    if (lane == 63) wtot[w] = inc;
    __syncthreads();
    if (t < 16) {
        int v = wtot[t];
        for (int o = 1; o < 16; o <<= 1) {
            int u = __shfl_up(v, o);
            if (t >= o) v += u;
        }
        wtot[t] = v;
    }
    __syncthreads();
    int run = (w > 0 ? wtot[w - 1] : 0) + (inc - s);
#pragma unroll
    for (int i = 0; i < 16; i++) {
        offs[base + i]   = run;
        cursor[base + i] = run;
        dinv[base + i]   = rsqrtf((float)(local[i] + 1));  // deg = indeg + self loop
        run += local[i];
    }
    if (t == 1023) offs[N_NODES] = run;
}

__global__ void k_scatter(const int* __restrict__ row, const int* __restrict__ col,
        int* __restrict__ cursor, const float* __restrict__ dinv,
        int* __restrict__ srcid, float* __restrict__ normv)
{
    int e = blockIdx.x * 256 + threadIdx.x;
    if (e >= E_EDGES) return;
    int r = row[e], c = col[e];
    int p = atomicAdd(&cursor[c], 1);
    srcid[p] = r;
    normv[p] = dinv[r] * dinv[c];
}

// ---------------- GCN aggregation (bf16 in, fp32 acc); unroll-4 gather; fused tpos --------
template<int W, int OUTF, int FUSET>
__global__ __launch_bounds__(128) void k_agg(const unsigned short* __restrict__ X,
        void* __restrict__ Y,
        const int* __restrict__ offs, const int* __restrict__ srcid,
        const float* __restrict__ normv, const float* __restrict__ dinv,
        const float* __restrict__ bias, int relu,
        const float* __restrict__ Wt, const float* __restrict__ bt,
        const float* __restrict__ pos, float* __restrict__ tposO)
{
    constexpr int NPB = (W == 128) ? 2 : 1;     // nodes per block (128 threads)
    constexpr int W2 = W / 2;
    const int local = (NPB == 2) ? (threadIdx.x >> 6) : 0;
    const int n = blockIdx.x * NPB + local;
    const int j = (NPB == 2) ? (threadIdx.x & 63) : threadIdx.x;
    const unsigned int* Xu = (const unsigned int*)X;
    float di = dinv[n];
    float w0 = di * di;
    unsigned int v = Xu[(size_t)n * W2 + j];
    float a0 = b2f((unsigned short)v) * w0;
    float a1 = b2f((unsigned short)(v >> 16)) * w0;
    int p = offs[n];
    const int p1 = offs[n + 1];
    for (; p + 3 < p1; p += 4) {
        int s0i = srcid[p], s1i = srcid[p + 1], s2i = srcid[p + 2], s3i = srcid[p + 3];
        float n0 = normv[p], n1 = normv[p + 1], n2 = normv[p + 2], n3 = normv[p + 3];
        unsigned int v0 = Xu[(size_t)s0i * W2 + j];
        unsigned int v1 = Xu[(size_t)s1i * W2 + j];
        unsigned int v2 = Xu[(size_t)s2i * W2 + j];
        unsigned int v3 = Xu[(size_t)s3i * W2 + j];
        a0 = fmaf(b2f((unsigned short)v0), n0, a0);
        a1 = fmaf(b2f((unsigned short)(v0 >> 16)), n0, a1);
        a0 = fmaf(b2f((unsigned short)v1), n1, a0);
        a1 = fmaf(b2f((unsigned short)(v1 >> 16)), n1, a1);
        a0 = fmaf(b2f((unsigned short)v2), n2, a0);
        a1 = fmaf(b2f((unsigned short)(v2 >> 16)), n2, a1);
        a0 = fmaf(b2f((unsigned short)v3), n3, a0);
        a1 = fmaf(b2f((unsigned short)(v3 >> 16)), n3, a1);
    }
    for (; p < p1; ++p) {
        unsigned int va = Xu[(size_t)srcid[p] * W2 + j]; float na = normv[p];
        a0 = fmaf(b2f((unsigned short)va), na, a0);
        a1 = fmaf(b2f((unsigned short)(va >> 16)), na, a1);
    }
    if (bias) { a0 += bias[2 * j]; a1 += bias[2 * j + 1]; }
    if (relu) { a0 = fmaxf(a0, 0.f); a1 = fmaxf(a1, 0.f); }
    if (OUTF) {
        float* Yf = (float*)Y;
        Yf[(size_t)n * W + 2 * j]     = a0;
        Yf[(size_t)n * W + 2 * j + 1] = a1;
    } else {
        ((unsigned int*)Y)[(size_t)n * W2 + j] =
            (unsigned int)f2b(a0) | ((unsigned int)f2b(a1) << 16);
    }
    if (FUSET) {   // tpos = pos + h @ Wt + bt, wave-per-node (W==128 only)
        float wt0 = Wt[6 * j + 0], wt1 = Wt[6 * j + 1], wt2 = Wt[6 * j + 2];
        float wt3 = Wt[6 * j + 3], wt4 = Wt[6 * j + 4], wt5 = Wt[6 * j + 5];
        float s0 = a0 * wt0 + a1 * wt3;
        float s1 = a0 * wt1 + a1 * wt4;
        float s2 = a0 * wt2 + a1 * wt5;
        for (int o = 32; o > 0; o >>= 1) {
            s0 += __shfl_down(s0, o);
            s1 += __shfl_down(s1, o);
            s2 += __shfl_down(s2, o);
        }
        if (j == 0) {
            tposO[n * 3 + 0] = pos[n * 3 + 0] + s0 + bt[0];
            tposO[n * 3 + 1] = pos[n * 3 + 1] + s1 + bt[1];
            tposO[n * 3 + 2] = pos[n * 3 + 2] + s2 + bt[2];
        }
    }
}

// ---------------- bf16 MFMA GEMM: C[M,N] = A[M,K] @ Bt[N,K]^T (+bias,relu) ----------------
__global__ __launch_bounds__(256) void k_gemm_bf16(
    const unsigned short* __restrict__ A,   // [M][K] bf16
    const unsigned short* __restrict__ Bt,  // [N][K] bf16
    const float* __restrict__ bias, unsigned short* __restrict__ C,
    int M, int N, int K, int relu)
{
    __shared__ __align__(16) unsigned short As[128 * 64];
    __shared__ __align__(16) unsigned short Bs[64 * 64];
    const int tid  = threadIdx.x;
    const int lane = tid & 63;
    const int wave = tid >> 6;
    const int bm = blockIdx.y * 128, bn = blockIdx.x * 64;
    const int wm = (wave >> 1) * 64, wn = (wave & 1) * 32;
    f32x4 acc[4][2];
#pragma unroll
    for (int mf = 0; mf < 4; mf++)
#pragma unroll
        for (int nf = 0; nf < 2; nf++) acc[mf][nf] = (f32x4){0.f, 0.f, 0.f, 0.f};

    for (int k0 = 0; k0 < K; k0 += 64) {
#pragma unroll
        for (int i = 0; i < 4; i++) {
            int idx = i * 256 + tid;
            int m = idx >> 3, slot = idx & 7;
            const unsigned short* src = A + (size_t)(bm + m) * K + k0 + ((slot ^ (m & 7)) << 3);
            __builtin_amdgcn_global_load_lds(
                (const __attribute__((address_space(1))) unsigned int*)src,
                (__attribute__((address_space(3))) unsigned int*)(As + (size_t)i * 2048 + wave * 512),
                16, 0, 0);
        }
#pragma unroll
        for (int i = 0; i < 2; i++) {
            int idx = i * 256 + tid;
            int n = idx >> 3, slot = idx & 7;
            const unsigned short* src = Bt + (size_t)(bn + n) * K + k0 + ((slot ^ (n & 7)) << 3);
            __builtin_amdgcn_global_load_lds(
                (const __attribute__((address_space(1))) unsigned int*)src,
                (__attribute__((address_space(3))) unsigned int*)(Bs + (size_t)i * 2048 + wave * 512),
                16, 0, 0);
        }
        __syncthreads();
        bf16x8 af[4][2], bfr[2][2];
        const int qd = lane >> 4;
#pragma unroll
        for (int s = 0; s < 2; s++) {
#pragma unroll
            for (int mf = 0; mf < 4; mf++) {
                int m = wm + mf * 16 + (lane & 15);
                int slot = (s * 4 + qd) ^ (m & 7);
                af[mf][s] = *(const bf16x8*)(As + m * 64 + slot * 8);
            }
#pragma unroll
            for (int nf = 0; nf < 2; nf++) {
                int n = wn + nf * 16 + (lane & 15);
                int slot = (s * 4 + qd) ^ (n & 7);
                bfr[nf][s] = *(const bf16x8*)(Bs + n * 64 + slot * 8);
            }
        }
#pragma unroll
        for (int s = 0; s < 2; s++)
#pragma unroll
            for (int mf = 0; mf < 4; mf++)
#pragma unroll
                for (int nf = 0; nf < 2; nf++)
                    acc[mf][nf] = __builtin_amdgcn_mfma_f32_16x16x32_bf16(
                        af[mf][s], bfr[nf][s], acc[mf][nf], 0, 0, 0);
        __syncthreads();
    }
#pragma unroll
    for (int nf = 0; nf < 2; nf++) {
        int col = bn + wn + nf * 16 + (lane & 15);
        float bv = bias ? bias[col] : 0.f;
#pragma unroll
        for (int mf = 0; mf < 4; mf++) {
#pragma unroll
            for (int r = 0; r < 4; r++) {
                int row = bm + wm + mf * 16 + (lane >> 4) * 4 + r;
                float v = acc[mf][nf][r] + bv;
                if (relu) v = fmaxf(v, 0.f);
                C[(size_t)row * N + col] = f2b(v);
            }
        }
    }
}

// ---------------- persistent ICP (10 iters) + chamfer + loss, ONE launch ------------------
// Proven R6 structure (256 blocks x 512 thr, double-buffered partials, redundant parallel
// gather+SVD per block). NEW arrival mechanism: NO shared counter -- each block publishes
// an iteration tag in slot 15 of its OWN partials line (release-ordered by the vmcnt-drain
// of __syncthreads); readers poll 32 independent lines with 32 parallel lanes. Removes the
// same-line atomicAdd convoy + spin flood.
__global__ __launch_bounds__(512) void k_icp_all(
    const float* __restrict__ tpos, const float* __restrict__ pos,
    float* __restrict__ partials,   // [2][256][16]; slot15 = iteration tag (zeroed per call)
    float* __restrict__ chpart,     // [256][2]
    int* __restrict__ ctrs,         // [128]=chamfer arrival (zeroed per call)
    float* __restrict__ out_aligned, float* __restrict__ out_loss)
{
    const int g = blockIdx.x >> 5, blk = blockIdx.x & 31;
    const int tid = threadIdx.x;
    const int wave = tid >> 6, lane = tid & 63;
    __shared__ float4 tq[NPG_];                                // 32KB, swizzled, w=|t|^2
    __shared__ __align__(16) unsigned char scratch[NPG_ * 16]; // 32KB union (sm_d/sm_i | al)
    float* sm_d = (float*)scratch;                             // [64][65]
    unsigned short* sm_i = (unsigned short*)(scratch + 64 * 65 * 4);
    float4* al = (float4*)scratch;                             // chamfer phase only
    __shared__ float mom[15][33];
    __shared__ float ssx[64], ssy[64], ssz[64];
    __shared__ float wred[8][2];
    __shared__ float Tsh[12];
    __shared__ double sdl[15];
    __shared__ int lastFlag;

    for (int i = tid; i < NPG_; i += 512) {
        const float* p = &pos[(size_t)(g * NPG_ + i) * 3];
        float qx = p[0], qy = p[1], qz = p[2];
        tq[swz32(i)] = make_float4(qx, qy, qz, fmaf(qx, qx, fmaf(qy, qy, qz * qz)));
    }
    if (tid < 12) Tsh[tid] = (tid == 0 || tid == 4 || tid == 8) ? 1.f : 0.f;
    // own 64 source points (8 per wave) in registers for all 10 iterations
    float Px[8], Py[8], Pz[8];
#pragma unroll
    for (int u = 0; u < 8; u++) {
        int n = g * NPG_ + blk * 64 + wave * 8 + u;
        Px[u] = tpos[n * 3 + 0]; Py[u] = tpos[n * 3 + 1]; Pz[u] = tpos[n * 3 + 2];
    }
    double Td[12];
    if (tid == 0) {
#pragma unroll
        for (int k = 0; k < 12; k++) Td[k] = (k == 0 || k == 4 || k == 8) ? 1.0 : 0.0;
    }
    __syncthreads();

    for (int iter = 0; iter < ICP_IT; ++iter) {
        const int bufbase = (iter & 1) * 256;
        float Tf[12];
#pragma unroll
        for (int k = 0; k < 12; k++) Tf[k] = Tsh[k];
        float Sx[8], Sy[8], Sz[8], Tx[8], Ty[8], Tz[8], bd[8];
        int bi[8];
#pragma unroll
        for (int u = 0; u < 8; u++) {
            float X = Tf[0] * Px[u] + Tf[1] * Py[u] + Tf[2] * Pz[u] + Tf[9];
            float Y = Tf[3] * Px[u] + Tf[4] * Py[u] + Tf[5] * Pz[u] + Tf[10];
            float Z = Tf[6] * Px[u] + Tf[7] * Py[u] + Tf[8] * Pz[u] + Tf[11];
            Sx[u] = X; Sy[u] = Y; Sz[u] = Z;
            Tx[u] = -2.f * X; Ty[u] = -2.f * Y; Tz[u] = -2.f * Z;
            bd[u] = 1e30f; bi[u] = lane * 32;
        }
        const int qbase = lane * 32;
        for (int j = 0; j < 32; j++) {
            float4 t4 = tq[qbase + (j ^ (lane & 31))];
            int idx = qbase + j;
#pragma unroll
            for (int u = 0; u < 8; u++) {
                // d' = |t|^2 - 2 s.t  (monotone in true distance)
                float d = fmaf(Tx[u], t4.x, fmaf(Ty[u], t4.y, fmaf(Tz[u], t4.z, t4.w)));
                if (d < bd[u]) { bd[u] = d; bi[u] = idx; }
            }
        }
        // stage candidates + transformed src coords
#pragma unroll
        for (int u = 0; u < 8; u++) {
            int row = wave * 8 + u;
            sm_d[row * 65 + lane] = bd[u];
            sm_i[row * 65 + lane] = (unsigned short)bi[u];
            if (lane == u) { ssx[row] = Sx[u]; ssy[row] = Sy[u]; ssz[row] = Sz[u]; }
        }
        __syncthreads();
        // wave 0: per-src argmin over 64 lane-slices (ranges ascend -> strict < = first idx),
        // then 15 block-moment shuffle sums; lane 0 publishes moments (agent stores).
        if (tid < 64) {
            const int s = tid;
            float best = sm_d[s * 65];
            int ib = sm_i[s * 65];
            for (int r = 1; r < 64; r++) {
                float dd = sm_d[s * 65 + r];
                int ii = sm_i[s * 65 + r];
                if (dd < best) { best = dd; ib = ii; }
            }
            float4 c = tq[swz32(ib)];
            float X = ssx[s], Y = ssy[s], Z = ssz[s];
            float vals[15] = { X, Y, Z, c.x, c.y, c.z,
                               X * c.x, X * c.y, X * c.z,
                               Y * c.x, Y * c.y, Y * c.z,
                               Z * c.x, Z * c.y, Z * c.z };
#pragma unroll
            for (int k = 0; k < 15; k++) {
                float v = vals[k];
                for (int o = 32; o > 0; o >>= 1) v += __shfl_down(v, o);
                if (tid == 0) st_agent(&partials[((size_t)bufbase + blockIdx.x) * 16 + k], v);
            }
        }
        __syncthreads();          // vmcnt(0) drain -> moment stores globally visible
        // release-publish this block's tag (own line, slot 15), then acquire-poll all 32
        if (tid == 0)
            st_agent_i((int*)partials + ((size_t)bufbase + blockIdx.x) * 16 + 15, iter + 1);
        if (tid < 32) {
            const int* tp = (const int*)partials + ((size_t)bufbase + g * 32 + tid) * 16 + 15;
            while (ld_agent_i(tp) < iter + 1) __builtin_amdgcn_s_sleep(1);
        }
        __syncthreads();
        // parallel gather: 480 agent loads (lines already warmed by tag polls)
        if (tid < 480) {
            int kk = tid >> 5, bb = tid & 31;
            mom[kk][bb] = ld_agent(&partials[((size_t)bufbase + g * 32 + bb) * 16 + kk]);
        }
        __syncthreads();
        if (tid < 15) {
            double acc = 0;
            for (int b = 0; b < NN_BPG; b++) acc += (double)mom[tid][b];
            sdl[tid] = acc;
        }
        __syncthreads();
        if (tid == 0) {
            double sd[15];
#pragma unroll
            for (int k = 0; k < 15; k++) sd[k] = sdl[k];
            const double n = (double)NPG_;
            const double rin = 1.0 / (double)NPG_;
            double cs0 = sd[0] * rin, cs1 = sd[1] * rin, cs2 = sd[2] * rin;
            double cc0 = sd[3] * rin, cc1 = sd[4] * rin, cc2 = sd[5] * rin;
            float H[3][3];
            H[0][0] = (float)(sd[6]  - n * cs0 * cc0); H[0][1] = (float)(sd[7]  - n * cs0 * cc1); H[0][2] = (float)(sd[8]  - n * cs0 * cc2);
            H[1][0] = (float)(sd[9]  - n * cs1 * cc0); H[1][1] = (float)(sd[10] - n * cs1 * cc1); H[1][2] = (float)(sd[11] - n * cs1 * cc2);
            H[2][0] = (float)(sd[12] - n * cs2 * cc0); H[2][1] = (float)(sd[13] - n * cs2 * cc1); H[2][2] = (float)(sd[14] - n * cs2 * cc2);
            double R[3][3];
            float fn = 1e-30f;
            for (int i = 0; i < 3; i++) for (int j2 = 0; j2 < 3; j2++) fn += H[i][j2] * H[i][j2];
            float sc = rsqrtf(fn);
            float Xm[3][3];
            for (int i = 0; i < 3; i++) for (int j2 = 0; j2 < 3; j2++) Xm[i][j2] = H[i][j2] * sc;
            float dX = Xm[0][0] * (Xm[1][1]*Xm[2][2] - Xm[1][2]*Xm[2][1])
                     - Xm[0][1] * (Xm[1][0]*Xm[2][2] - Xm[1][2]*Xm[2][0])
                     + Xm[0][2] * (Xm[1][0]*Xm[2][1] - Xm[1][1]*Xm[2][0]);
            if (dX > 1e-4f) {
                // polar Newton: X <- 0.5*(X + cof(X)/det(X)); R_ref = Q^T
                for (int itn = 0; itn < 16; ++itn) {
                    float C00 = Xm[1][1]*Xm[2][2] - Xm[1][2]*Xm[2][1];
                    float C01 = Xm[1][2]*Xm[2][0] - Xm[1][0]*Xm[2][2];
                    float C02 = Xm[1][0]*Xm[2][1] - Xm[1][1]*Xm[2][0];
                    float C10 = Xm[2][1]*Xm[0][2] - Xm[2][2]*Xm[0][1];
                    float C11 = Xm[2][2]*Xm[0][0] - Xm[2][0]*Xm[0][2];
                    float C12 = Xm[2][0]*Xm[0][1] - Xm[2][1]*Xm[0][0];
                    float C20 = Xm[0][1]*Xm[1][2] - Xm[0][2]*Xm[1][1];
                    float C21 = Xm[0][2]*Xm[1][0] - Xm[0][0]*Xm[1][2];
                    float C22 = Xm[0][0]*Xm[1][1] - Xm[0][1]*Xm[1][0];
                    float det = Xm[0][0]*C00 + Xm[0][1]*C01 + Xm[0][2]*C02;
                    if (fabsf(det) < 1e-30f) break;
                    float rd = 0.5f / det;
                    Xm[0][0] = 0.5f*Xm[0][0] + C00*rd; Xm[0][1] = 0.5f*Xm[0][1] + C01*rd; Xm[0][2] = 0.5f*Xm[0][2] + C02*rd;
                    Xm[1][0] = 0.5f*Xm[1][0] + C10*rd; Xm[1][1] = 0.5f*Xm[1][1] + C11*rd; Xm[1][2] = 0.5f*Xm[1][2] + C12*rd;
                    Xm[2][0] = 0.5f*Xm[2][0] + C20*rd; Xm[2][1] = 0.5f*Xm[2][1] + C21*rd; Xm[2][2] = 0.5f*Xm[2][2] + C22*rd;
                }
                for (int i = 0; i < 3; i++) for (int j2 = 0; j2 < 3; j2++) R[i][j2] = (double)Xm[j2][i];
            } else {
                // Jacobi-SVD fallback (deterministic)
                float A[3][3], V[3][3] = {{1,0,0},{0,1,0},{0,0,1}};
                for (int i = 0; i < 3; i++)
                    for (int j2 = 0; j2 < 3; j2++)
                        A[i][j2] = H[0][i] * H[0][j2] + H[1][i] * H[1][j2] + H[2][i] * H[2][j2];
                for (int sweep = 0; sweep < 8; ++sweep) {
                    for (int p = 0; p < 2; p++) for (int q = p + 1; q < 3; q++) {
                        float apq = A[p][q];
                        if (fabsf(apq) < 1e-30f) continue;
                        float theta = (A[q][q] - A[p][p]) / (2.f * apq);
                        float t = copysignf(1.f, theta) / (fabsf(theta) + sqrtf(theta * theta + 1.f));
                        float c = 1.f / sqrtf(t * t + 1.f);
                        float s = t * c;
                        for (int k = 0; k < 3; k++) { float akp = A[k][p], akq = A[k][q]; A[k][p] = c*akp - s*akq; A[k][q] = s*akp + c*akq; }
                        for (int k = 0; k < 3; k++) { float apk = A[p][k], aqk = A[q][k]; A[p][k] = c*apk - s*aqk; A[q][k] = s*apk + c*aqk; }
                        for (int k = 0; k < 3; k++) { float vkp = V[k][p], vkq = V[k][q]; V[k][p] = c*vkp - s*vkq; V[k][q] = s*vkp + c*vkq; }
                    }
                }
                float lam[3] = { A[0][0], A[1][1], A[2][2] };
                int ord[3] = { 0, 1, 2 };
                if (lam[ord[1]] > lam[ord[0]]) { int t0 = ord[0]; ord[0] = ord[1]; ord[1] = t0; }
                if (lam[ord[2]] > lam[ord[0]]) { int t0 = ord[0]; ord[0] = ord[2]; ord[2] = t0; }
                if (lam[ord[2]] > lam[ord[1]]) { int t0 = ord[1]; ord[1] = ord[2]; ord[2] = t0; }
                float vc[3][3], uc[3][3];
                for (int i = 0; i < 3; i++) { vc[i][0] = V[0][ord[i]]; vc[i][1] = V[1][ord[i]]; vc[i][2] = V[2][ord[i]]; }
                for (int i = 0; i < 3; i++) {
                    float u0 = H[0][0]*vc[i][0] + H[0][1]*vc[i][1] + H[0][2]*vc[i][2];
                    float u1 = H[1][0]*vc[i][0] + H[1][1]*vc[i][1] + H[1][2]*vc[i][2];
                    float u2 = H[2][0]*vc[i][0] + H[2][1]*vc[i][1] + H[2][2]*vc[i][2];
                    for (int j2 = 0; j2 < i; j2++) {
                        float dp = u0*uc[j2][0] + u1*uc[j2][1] + u2*uc[j2][2];
                        u0 -= dp*uc[j2][0]; u1 -= dp*uc[j2][1]; u2 -= dp*uc[j2][2];
                    }
                    float nn2 = sqrtf(u0*u0 + u1*u1 + u2*u2);
                    if (nn2 > 1e-12f) { uc[i][0] = u0/nn2; uc[i][1] = u1/nn2; uc[i][2] = u2/nn2; }
                    else if (i == 2) {
                        uc[2][0] = uc[0][1]*uc[1][2] - uc[0][2]*uc[1][1];
                        uc[2][1] = uc[0][2]*uc[1][0] - uc[0][0]*uc[1][2];
                        uc[2][2] = uc[0][0]*uc[1][1] - uc[0][1]*uc[1][0];
                    } else if (i == 1) {
                        float a0 = (fabsf(uc[0][0]) < 0.9f) ? 1.f : 0.f, a1 = 1.f - a0, a2 = 0.f;
                        float dp = a0*uc[0][0] + a1*uc[0][1] + a2*uc[0][2];
                        a0 -= dp*uc[0][0]; a1 -= dp*uc[0][1]; a2 -= dp*uc[0][2];
                        float nn3 = sqrtf(a0*a0 + a1*a1 + a2*a2);
                        uc[1][0] = a0/nn3; uc[1][1] = a1/nn3; uc[1][2] = a2/nn3;
                    } else { uc[0][0] = 1; uc[0][1] = 0; uc[0][2] = 0; }
                }
                float detU = uc[0][0]*(uc[1][1]*uc[2][2] - uc[1][2]*uc[2][1])
                           - uc[0][1]*(uc[1][0]*uc[2][2] - uc[1][2]*uc[2][0])
                           + uc[0][2]*(uc[1][0]*uc[2][1] - uc[1][1]*uc[2][0]);
                float detV = vc[0][0]*(vc[1][1]*vc[2][2] - vc[1][2]*vc[2][1])
                           - vc[0][1]*(vc[1][0]*vc[2][2] - vc[1][2]*vc[2][0])
                           + vc[0][2]*(vc[1][0]*vc[2][1] - vc[1][1]*vc[2][0]);
                float sgn = (detU * detV < 0.f) ? -1.f : 1.f;
                for (int i = 0; i < 3; i++)
                    for (int j2 = 0; j2 < 3; j2++)
                        R[i][j2] = (double)(vc[0][i]*uc[0][j2] + vc[1][i]*uc[1][j2] + sgn * vc[2][i]*uc[2][j2]);
            }
            double tr0 = cc0 - (R[0][0]*cs0 + R[0][1]*cs1 + R[0][2]*cs2);
            double tr1 = cc1 - (R[1][0]*cs0 + R[1][1]*cs1 + R[1][2]*cs2);
            double tr2 = cc2 - (R[2][0]*cs0 + R[2][1]*cs1 + R[2][2]*cs2);
            double An[12];
            for (int i = 0; i < 3; i++)
                for (int j2 = 0; j2 < 3; j2++)
                    An[i*3+j2] = R[i][0]*Td[0*3+j2] + R[i][1]*Td[1*3+j2] + R[i][2]*Td[2*3+j2];
            An[9]  = R[0][0]*Td[9] + R[0][1]*Td[10] + R[0][2]*Td[11] + tr0;
            An[10] = R[1][0]*Td[9] + R[1][1]*Td[10] + R[1][2]*Td[11] + tr1;
            An[11] = R[2][0]*Td[9] + R[2][1]*Td[10] + R[2][2]*Td[11] + tr2;
#pragma unroll
            for (int k = 0; k < 12; k++) { Td[k] = An[k]; Tsh[k] = (float)An[k]; }
        }
        __syncthreads();
    }

    // ---- chamfer phase: aligned into LDS (final T), both directions, last-block loss ----
    {
        float Tf[12];
#pragma unroll
        for (int k = 0; k < 12; k++) Tf[k] = Tsh[k];
        __syncthreads();   // sm_d/sm_i dead; al aliases scratch
        for (int i = tid; i < NPG_; i += 512) {
            const float* q = &tpos[(size_t)(g * NPG_ + i) * 3];
            float X = Tf[0] * q[0] + Tf[1] * q[1] + Tf[2] * q[2] + Tf[9];
            float Y = Tf[3] * q[0] + Tf[4] * q[1] + Tf[5] * q[2] + Tf[10];
            float Z = Tf[6] * q[0] + Tf[7] * q[1] + Tf[8] * q[2] + Tf[11];
            al[swz32(i)] = make_float4(X, Y, Z, fmaf(X, X, fmaf(Y, Y, Z * Z)));
            if (blk == 0) {
                out_aligned[(size_t)(g * NPG_ + i) * 3 + 0] = X;
                out_aligned[(size_t)(g * NPG_ + i) * 3 + 1] = Y;
                out_aligned[(size_t)(g * NPG_ + i) * 3 + 2] = Z;
            }
        }
        __syncthreads();
        float Ax[8], Ay[8], Az[8], Aw[8], Qx[8], Qy[8], Qz[8], Qw[8], d1[8], d2[8];
#pragma unroll
        for (int u = 0; u < 8; u++) {
            int s = swz32(blk * 64 + wave * 8 + u);
            float4 a4 = al[s]; float4 p4 = tq[s];
            Ax[u] = -2.f * a4.x; Ay[u] = -2.f * a4.y; Az[u] = -2.f * a4.z; Aw[u] = a4.w;
            Qx[u] = -2.f * p4.x; Qy[u] = -2.f * p4.y; Qz[u] = -2.f * p4.z; Qw[u] = p4.w;
            d1[u] = 1e30f; d2[u] = 1e30f;
        }
        const int qbase = lane * 32;
        for (int j = 0; j < 32; j++) {
            int s = qbase + (j ^ (lane & 31));
            float4 t4 = tq[s];
            float4 b4 = al[s];
#pragma unroll
            for (int u = 0; u < 8; u++) {
                d1[u] = fminf(d1[u], fmaf(Ax[u], t4.x, fmaf(Ay[u], t4.y, fmaf(Az[u], t4.z, t4.w))));
                d2[u] = fminf(d2[u], fmaf(Qx[u], b4.x, fmaf(Qy[u], b4.y, fmaf(Qz[u], b4.z, b4.w))));
            }
        }
        float s1 = 0.f, s2 = 0.f;
#pragma unroll
        for (int u = 0; u < 8; u++) {
            float a = d1[u], b = d2[u];
            for (int o = 32; o > 0; o >>= 1) {
                a = fminf(a, __shfl_down(a, o));
                b = fminf(b, __shfl_down(b, o));
            }
            s1 += a + Aw[u];     // + |src|^2 completes the squared distance
            s2 += b + Qw[u];
        }
        if (lane == 0) { wred[wave][0] = s1; wred[wave][1] = s2; }
        __syncthreads();
        if (tid == 0) {
            float t1 = 0.f, t2 = 0.f;
#pragma unroll
            for (int w = 0; w < 8; w++) { t1 += wred[w][0]; t2 += wred[w][1]; }
            st_agent(&chpart[blockIdx.x * 2 + 0], t1);
            st_agent(&chpart[blockIdx.x * 2 + 1], t2);
        }
        __syncthreads();
        if (tid == 0) {
            int old = atomicAdd(&ctrs[128], 1);
            lastFlag = (old == (int)gridDim.x - 1) ? 1 : 0;
        }
        __syncthreads();
        if (!lastFlag) return;
        float v1 = 0.f, v2 = 0.f;
        if (tid < 256) {
            v1 = ld_agent(&chpart[tid * 2 + 0]);
            v2 = ld_agent(&chpart[tid * 2 + 1]);
        }
        for (int o = 32; o > 0; o >>= 1) {
            v1 += __shfl_down(v1, o);
            v2 += __shfl_down(v2, o);
        }
        if (lane == 0 && wave < 4) { wred[wave][0] = v1; wred[wave][1] = v2; }
        __syncthreads();
        if (tid == 0) {
            float tot = 0.f;
#pragma unroll
            for (int w = 0; w < 4; w++) tot += wred[w][0] + wred[w][1];
            out_loss[0] = tot / (float)(NPG_ * B_GRAPHS);
        }
    }
}

// ---------------- launcher ----------------
extern "C" void kernel_launch(void* const* d_in, const int* in_sizes, int n_in,
                              void* d_out, int out_size, void* d_ws, size_t ws_size,
                              hipStream_t stream)
{
    (void)in_sizes; (void)n_in; (void)out_size; (void)ws_size;
    const float* x   = (const float*)d_in[0];
    const int*   ei  = (const int*)d_in[1];
    const float* pos = (const float*)d_in[2];
    const float* W1 = (const float*)d_in[4];
    const float* b1 = (const float*)d_in[5];
    const float* W2 = (const float*)d_in[6];
    const float* b2 = (const float*)d_in[7];
    const float* W3 = (const float*)d_in[8];
    const float* b3 = (const float*)d_in[9];
    const float* Wt = (const float*)d_in[10];
    const float* bt = (const float*)d_in[11];
    const int* row = ei;
    const int* col = ei + E_EDGES;

    char* wsb = (char*)d_ws;
    size_t off_b = 0;
    auto alloc = [&](size_t bytes) -> void* {
        void* p = wsb + off_b;
        off_b = (off_b + bytes + 255) & ~(size_t)255;
        return p;
    };
    // contiguous zero region: counts (64KB) + partials (32KB) + ctrs (1KB) = 99328 B
    int*    counts   = (int*)alloc((size_t)N_NODES * 4);
    float*  partials = (float*)alloc((size_t)2 * 256 * 16 * 4);
    int*    ctrs     = (int*)alloc((size_t)256 * 4);
    int*    offs     = (int*)alloc((size_t)(N_NODES + 1) * 4);
    int*    cursor   = (int*)alloc((size_t)N_NODES * 4);
    int*    srcid    = (int*)alloc((size_t)E_EDGES * 4);
    float*  normv    = (float*)alloc((size_t)E_EDGES * 4);
    float*  dinv     = (float*)alloc((size_t)N_NODES * 4);
    unsigned short* xb  = (unsigned short*)alloc((size_t)N_NODES * F_IN * 2);
    unsigned short* W1b = (unsigned short*)alloc((size_t)F_IN * F_HID * 2);
    unsigned short* W2b = (unsigned short*)alloc((size_t)F_HID * F_HID * 2);
    unsigned short* W3b = (unsigned short*)alloc((size_t)F_HID * F_OUT * 2);
    unsigned short* bufA = (unsigned short*)alloc((size_t)N_NODES * F_HID * 2);
    unsigned short* bufB = (unsigned short*)alloc((size_t)N_NODES * F_HID * 2);
    unsigned short* bufC = (unsigned short*)alloc((size_t)N_NODES * F_HID * 2);
    float*  tpos     = (float*)alloc((size_t)N_NODES * 3 * 4);
    float*  chpart   = (float*)alloc((size_t)256 * 2 * 4);

    float* out_h       = (float*)d_out;
    float* out_aligned = out_h + (size_t)N_NODES * F_OUT;
    float* out_loss    = out_aligned + (size_t)N_NODES * 3;

    // 1: zero counts + partials(tags) + ctrs in ONE stream-ordered memset (replay-safe)
    hipMemsetAsync(counts, 0, (size_t)N_NODES * 4 + 2 * 256 * 16 * 4 + 256 * 4, stream);
    // 2: converts + edge count
    k_prep<<<3584, 256, 0, stream>>>(x, xb, W1, W2, W3, W1b, W2b, W3b, col, counts);
    // 3-4: CSR
    k_scan<<<1, 1024, 0, stream>>>(counts, offs, cursor, dinv);
    k_scatter<<<E_EDGES / 256, 256, 0, stream>>>(row, col, cursor, dinv, srcid, normv);

    // 5: layer1 aggregate (x bf16 -> bufA)
    k_agg<F_IN, 0, 0><<<N_NODES / 2, 128, 0, stream>>>(xb, bufA, offs, srcid, normv, dinv,
            nullptr, 0, nullptr, nullptr, nullptr, nullptr);
    // 6: gemm1 + bias + relu
    {
        dim3 grid(F_HID / 64, N_NODES / 128);
        k_gemm_bf16<<<grid, 256, 0, stream>>>(bufA, W1b, b1, bufB, N_NODES, F_HID, F_IN, 1);
    }
    // 7: gemm2 (no bias)
    {
        dim3 grid(F_HID / 64, N_NODES / 128);
        k_gemm_bf16<<<grid, 256, 0, stream>>>(bufB, W2b, nullptr, bufC, N_NODES, F_HID, F_HID, 0);
    }
    // 8: layer2 aggregate + b2 + relu
    k_agg<F_HID, 0, 0><<<N_NODES, 128, 0, stream>>>(bufC, bufA, offs, srcid, normv, dinv,
            b2, 1, nullptr, nullptr, nullptr, nullptr);
    // 9: gemm3
    {
        dim3 grid(F_OUT / 64, N_NODES / 128);
        k_gemm_bf16<<<grid, 256, 0, stream>>>(bufA, W3b, nullptr, bufB, N_NODES, F_OUT, F_HID, 0);
    }
    // 10: layer3 aggregate + b3 -> out_h (fp32), fused tpos
    k_agg<F_OUT, 1, 1><<<N_NODES / 2, 128, 0, stream>>>(bufB, out_h, offs, srcid, normv, dinv,
            b3, 0, Wt, bt, pos, tpos);

    // 11: persistent ICP (10 iterations) + apply + chamfer + loss (256 blocks, 1/CU)
    k_icp_all<<<B_GRAPHS * NN_BPG, 512, 0, stream>>>(tpos, pos, partials, chpart, ctrs,
            out_aligned, out_loss);
}